// Round 6
// baseline (7027.736 us; speedup 1.0000x reference)
//
#include <hip/hip_runtime.h>

#define L 10

using bf16x8 = __attribute__((ext_vector_type(8))) __bf16;
using u16x8  = __attribute__((ext_vector_type(8))) unsigned short;
using f32x4  = __attribute__((ext_vector_type(4))) float;

__device__ __forceinline__ unsigned short f2bf(float f) {
  unsigned int u = __float_as_uint(f);
  u += 0x7FFFu + ((u >> 16) & 1u);          // RNE
  return (unsigned short)(u >> 16);
}
__device__ __forceinline__ float bf2f(unsigned short h) {
  return __uint_as_float(((unsigned int)h) << 16);
}

// ---------------------------------------------------------------------------
// Plaquette: single thread, exact fp32, matching JAX trunc-cast + python mod.
// ---------------------------------------------------------------------------
__global__ void plaq_kernel(const float* __restrict__ x,
                            const float* __restrict__ field,
                            float* __restrict__ out) {
  if (threadIdx.x != 0 || blockIdx.x != 0) return;
  int c[4];
#pragma unroll
  for (int i = 0; i < 4; ++i) {
    int v = (int)x[i];
    v %= L; if (v < 0) v += L;
    c[i] = v;
  }
  float S = 0.f;
  for (int mu = 0; mu < 4; ++mu)
    for (int nu = mu + 1; nu < 4; ++nu) {
      int p[4] = {c[0], c[1], c[2], c[3]};
      float l1 = field[((p[0]*L + p[1])*L + p[2])*4 + mu];
      p[mu] = (p[mu] + 1) % L;
      float l2 = field[((p[0]*L + p[1])*L + p[2])*4 + nu];
      p[nu] = (p[nu] + 1) % L;
      float l3 = field[((p[0]*L + p[1])*L + p[2])*4 + mu];
      float l4 = field[((c[0]*L + c[1])*L + c[2])*4 + nu];
      S += l1 + l2 - l3 - l4;
    }
  out[0] = expf(S);
}

// ---------------------------------------------------------------------------
// fc1: h = relu(x[16384,4] @ fw1[4,2048] + fb1) -> bf16.
// ---------------------------------------------------------------------------
__global__ void fc1_kernel(const float* __restrict__ x,
                           const float* __restrict__ fw1,
                           const float* __restrict__ fb1,
                           unsigned short* __restrict__ h) {
  const int N = 2048;
  int idx = blockIdx.x * blockDim.x + threadIdx.x;
  int m  = idx >> 8;
  int n0 = (idx & 255) * 8;
  float4 xv = *(const float4*)(x + (size_t)m * 4);
  unsigned short o[8];
#pragma unroll
  for (int j = 0; j < 8; ++j) {
    int n = n0 + j;
    float s = fb1[n] + xv.x * fw1[n] + xv.y * fw1[N + n]
                     + xv.z * fw1[2*N + n] + xv.w * fw1[3*N + n];
    o[j] = f2bf(fmaxf(s, 0.f));
  }
  *(u16x8*)(h + (size_t)m * N + n0) = *(const u16x8*)o;
}

// ---------------------------------------------------------------------------
// Weight transpose+convert: W[K][N] f32 -> WT[N][K] bf16.
// ---------------------------------------------------------------------------
__global__ void transpose_bf16_kernel(const float* __restrict__ W,
                                      unsigned short* __restrict__ WT,
                                      int K, int N) {
  __shared__ float tile[32][33];
  int n0 = blockIdx.x * 32, k0 = blockIdx.y * 32;
  int tx = threadIdx.x, ty = threadIdx.y;   // 32 x 8
#pragma unroll
  for (int i = 0; i < 32; i += 8)
    tile[ty + i][tx] = W[(size_t)(k0 + ty + i) * N + n0 + tx];
  __syncthreads();
#pragma unroll
  for (int i = 0; i < 32; i += 8)
    WT[(size_t)(n0 + ty + i) * K + k0 + tx] = f2bf(tile[tx][ty + i]);
}

// ---------------------------------------------------------------------------
// Elementwise f32 -> bf16 cast (natural layout), 8 elems/thread.
// ---------------------------------------------------------------------------
__global__ void cast_bf16_kernel(const float* __restrict__ in,
                                 unsigned short* __restrict__ out) {
  size_t i = ((size_t)blockIdx.x * blockDim.x + threadIdx.x) * 8;
  unsigned short o[8];
#pragma unroll
  for (int j = 0; j < 8; ++j) o[j] = f2bf(in[i + j]);
  *(u16x8*)(out + i) = *(const u16x8*)o;
}

// ---------------------------------------------------------------------------
// biascat: out[0:4096] = fb2; out[4096+m] = (m<2048?wb1[m]:tb1[m-2048])
//                                + sum_j catT[m][j]*fb2[j]    (wave per row)
// ---------------------------------------------------------------------------
__global__ void biascat_kernel(const unsigned short* __restrict__ catT,
                               const float* __restrict__ fb2,
                               const float* __restrict__ wb1,
                               const float* __restrict__ tb1,
                               float* __restrict__ out) {
  int w    = blockIdx.x * 4 + (threadIdx.x >> 6);   // 0..8191
  int lane = threadIdx.x & 63;
  if (w < 4096) { if (lane == 0) out[w] = fb2[w]; return; }
  int m = w - 4096;
  const unsigned short* row = catT + (size_t)m * 4096;
  float s = 0.f;
  for (int k = lane * 8; k < 4096; k += 512) {
    u16x8 v = *(const u16x8*)(row + k);
#pragma unroll
    for (int j = 0; j < 8; ++j) s += bf2f(v[j]) * fb2[k + j];
  }
#pragma unroll
  for (int off = 32; off; off >>= 1) s += __shfl_down(s, off);
  if (lane == 0) out[w] = s + (m < 2048 ? wb1[m] : tb1[m - 2048]);
}

// ---------------------------------------------------------------------------
// 128x128 bf16 MFMA GEMM (2 blocks/CU) for the weight product
// W2catT = (fw2 @ [ww1|tw1])^T.  C[m][n] = sum_k A[m,k]*BT[n,k], bf16 out.
// ---------------------------------------------------------------------------
__global__ __launch_bounds__(256, 2)
void gemm128_kernel(const unsigned short* __restrict__ A,
                    const unsigned short* __restrict__ BT,
                    unsigned short* __restrict__ outB,
                    int N, int K) {
  constexpr int BK = 64;
  __shared__ unsigned short As[128 * BK];
  __shared__ unsigned short Bs[128 * BK];

  const int bm = blockIdx.x, bn = blockIdx.y;
  const int tid = threadIdx.x;
  const int wid = tid >> 6, lane = tid & 63;
  const int wr = wid >> 1, wc = wid & 1;
  const int lr = lane & 15, lg = lane >> 4;

  f32x4 acc[4][4];
#pragma unroll
  for (int m = 0; m < 4; ++m)
#pragma unroll
    for (int n = 0; n < 4; ++n) acc[m][n] = (f32x4)0.f;

  const int srow = wid * 32 + (lane >> 3);
  const int scol = (lane & 7) * 8;
  const unsigned short* Ag = A  + (size_t)(bm * 128 + srow) * K + scol;
  const unsigned short* Bg = BT + (size_t)(bn * 128 + srow) * K + scol;

  for (int kt = 0; kt < K; kt += BK) {
#pragma unroll
    for (int i = 0; i < 4; ++i) {
      __builtin_amdgcn_global_load_lds(
          (const __attribute__((address_space(1))) unsigned int*)(Ag + (size_t)i * 8 * K + kt),
          (__attribute__((address_space(3))) unsigned int*)&As[wid * 2048 + i * 512],
          16, 0, 0);
      __builtin_amdgcn_global_load_lds(
          (const __attribute__((address_space(1))) unsigned int*)(Bg + (size_t)i * 8 * K + kt),
          (__attribute__((address_space(3))) unsigned int*)&Bs[wid * 2048 + i * 512],
          16, 0, 0);
    }
    __syncthreads();
#pragma unroll
    for (int kk = 0; kk < 2; ++kk) {
      u16x8 af[4], bf[4];
#pragma unroll
      for (int m = 0; m < 4; ++m)
        af[m] = *(const u16x8*)&As[(wr * 64 + m * 16 + lr) * BK + kk * 32 + lg * 8];
#pragma unroll
      for (int n = 0; n < 4; ++n)
        bf[n] = *(const u16x8*)&Bs[(wc * 64 + n * 16 + lr) * BK + kk * 32 + lg * 8];
#pragma unroll
      for (int m = 0; m < 4; ++m)
#pragma unroll
        for (int n = 0; n < 4; ++n)
          acc[m][n] = __builtin_amdgcn_mfma_f32_16x16x32_bf16(
              __builtin_bit_cast(bf16x8, af[m]),
              __builtin_bit_cast(bf16x8, bf[n]),
              acc[m][n], 0, 0, 0);
    }
    __syncthreads();
  }

  const int rowBase = bm * 128 + wr * 64 + lg * 4;
  const int colBase = bn * 128 + wc * 64 + lr;
#pragma unroll
  for (int n = 0; n < 4; ++n) {
    int col = colBase + n * 16;
#pragma unroll
    for (int m = 0; m < 4; ++m) {
      int row = rowBase + m * 16;
#pragma unroll
      for (int j = 0; j < 4; ++j)
        outB[(size_t)(row + j) * N + col] = f2bf(acc[m][n][j]);
    }
  }
}

// ---------------------------------------------------------------------------
// 256x256 bf16 MFMA GEMM, BK=32, ring-2 LDS (64KB) -> 2 blocks/CU (16 waves,
// m114 cross-block overlap covers the drain-0 gate). 8 waves (2Mx4N).
// Counted-lgkm read->MFMA interleave, zero-conflict XOR swizzle (T2),
// setprio (T5), bijective XCD swizzle (T1). Split epilogue:
//   bn <  nFtiles : C+bias -> f32 outF (no relu), row stride NF
//   bn >= nFtiles : relu(C+bias) -> bf16 outB at col-4096, row stride NB
// ---------------------------------------------------------------------------
#define GLL(gp, lp)                                                            \
  __builtin_amdgcn_global_load_lds(                                            \
      (const __attribute__((address_space(1))) unsigned int*)(gp),             \
      (__attribute__((address_space(3))) unsigned int*)(lp), 16, 0, 0)

#define DSREAD(dst, addr)                                                      \
  asm volatile("ds_read_b128 %0, %1" : "=v"(dst) : "v"(addr))

#define LGKM(n)                                                                \
  do { asm volatile("s_waitcnt lgkmcnt(" #n ")" ::: "memory");                 \
       __builtin_amdgcn_sched_barrier(0); } while (0)

#define FENCE() asm volatile("" ::: "memory")

extern __shared__ char lds_raw[];

__global__ __launch_bounds__(512, 4)
void gemm256_kernel(const unsigned short* __restrict__ A,
                    const unsigned short* __restrict__ BT,
                    const float* __restrict__ bias,
                    float* __restrict__ outF,
                    unsigned short* __restrict__ outB,
                    int lda, int K, int NF, int NB, int nFtiles, int gmx) {
  const int NT = K >> 5;                      // K32 tiles

  // T1: bijective XCD swizzle, bm fastest
  const int nwg = gridDim.x;
  const int q = nwg >> 3, r = nwg & 7;
  const int xcd = blockIdx.x & 7, lid = blockIdx.x >> 3;
  const int wg2 = (xcd < r ? xcd * (q + 1) : r * (q + 1) + (xcd - r) * q) + lid;
  const int bm = wg2 % gmx, bn = wg2 / gmx;

  const int tid  = threadIdx.x;
  const int wid  = tid >> 6, lane = tid & 63;
  const int wr   = wid >> 2, wc = wid & 3;          // 2 x 4 waves
  const int lr   = lane & 15, lg = lane >> 4;

  // ---- staging (pre-swizzled global source, linear LDS dest) ----
  const int srow = tid >> 2;
  const int scol = ((tid & 3) ^ ((tid >> 3) & 3)) * 8;   // elems
  const unsigned short* agp0 = A  + (size_t)(bm * 256 + srow) * lda + scol;
  const unsigned short* agp1 = agp0 + (size_t)128 * lda;
  const unsigned short* bgp0 = BT + (size_t)(bn * 256 + srow) * K + scol;
  const unsigned short* bgp1 = bgp0 + (size_t)128 * K;

  // ---- read-side swizzled fragment offsets (0 bank conflicts) ----
  const int chunk = lg ^ ((lr >> 1) & 3);
  const unsigned ldsbase = (unsigned)(uintptr_t)&lds_raw[0];
  const unsigned aoff = (unsigned)((wr * 128 + lr) * 64 + chunk * 16);
  const unsigned boff = (unsigned)(16384 + (wc * 64 + lr) * 64 + chunk * 16);

  f32x4 acc[8][4];
#pragma unroll
  for (int m = 0; m < 8; ++m)
#pragma unroll
    for (int n = 0; n < 4; ++n) acc[m][n] = (f32x4)0.f;

#define STAGE_A(tt) do { unsigned so = (unsigned)(((tt) & 1) << 15);           \
    GLL(agp0 + (size_t)(tt) * 32, lds_raw + so + tid * 16);                    \
    GLL(agp1 + (size_t)(tt) * 32, lds_raw + so + 8192 + tid * 16); } while (0)
#define STAGE_B(tt) do { unsigned so = (unsigned)(((tt) & 1) << 15);           \
    GLL(bgp0 + (size_t)(tt) * 32, lds_raw + so + 16384 + tid * 16);            \
    GLL(bgp1 + (size_t)(tt) * 32, lds_raw + so + 24576 + tid * 16); } while (0)

  // prologue: tile 0 staged
  STAGE_A(0); STAGE_B(0);

  for (int t = 0; t < NT; ++t) {
    // drain: tile t landed (its 4 loads are the only outstanding VMEM).
    // The co-resident block covers this stall (2 blocks/CU).
    asm volatile("s_waitcnt vmcnt(0)" ::: "memory");
    FENCE(); __builtin_amdgcn_s_barrier(); FENCE();
    __builtin_amdgcn_sched_barrier(0);

    // stage next tile immediately: max latency cover under this tile's MFMA
    if (t + 1 < NT) { STAGE_A(t + 1); STAGE_B(t + 1); }

    const unsigned sbase = ldsbase + (unsigned)((t & 1) << 15);

    // issue reads in consumption order: b0-3 then a0-7 (in-order DS returns)
    u16x8 b[4], a[8];
    DSREAD(b[0], sbase + boff);
    DSREAD(b[1], sbase + boff + 1024);
    DSREAD(b[2], sbase + boff + 2048);
    DSREAD(b[3], sbase + boff + 3072);
    DSREAD(a[0], sbase + aoff);
    DSREAD(a[1], sbase + aoff + 1024);
    DSREAD(a[2], sbase + aoff + 2048);
    DSREAD(a[3], sbase + aoff + 3072);
    DSREAD(a[4], sbase + aoff + 4096);
    DSREAD(a[5], sbase + aoff + 5120);
    DSREAD(a[6], sbase + aoff + 6144);
    DSREAD(a[7], sbase + aoff + 7168);

    // 8 clusters: counted lgkm gate -> 4 MFMA; LDS serves ahead under MFMA.
    // cluster 7's LGKM(0) retires all reads of this slot before the next
    // barrier, so next iteration's STAGE into this slot is race-free.
    __builtin_amdgcn_s_setprio(1);
#define CLUSTER(m, g)                                                          \
    LGKM(g);                                                                   \
    acc[m][0] = __builtin_amdgcn_mfma_f32_16x16x32_bf16(                       \
        __builtin_bit_cast(bf16x8, a[m]), __builtin_bit_cast(bf16x8, b[0]),    \
        acc[m][0], 0, 0, 0);                                                   \
    acc[m][1] = __builtin_amdgcn_mfma_f32_16x16x32_bf16(                       \
        __builtin_bit_cast(bf16x8, a[m]), __builtin_bit_cast(bf16x8, b[1]),    \
        acc[m][1], 0, 0, 0);                                                   \
    acc[m][2] = __builtin_amdgcn_mfma_f32_16x16x32_bf16(                       \
        __builtin_bit_cast(bf16x8, a[m]), __builtin_bit_cast(bf16x8, b[2]),    \
        acc[m][2], 0, 0, 0);                                                   \
    acc[m][3] = __builtin_amdgcn_mfma_f32_16x16x32_bf16(                       \
        __builtin_bit_cast(bf16x8, a[m]), __builtin_bit_cast(bf16x8, b[3]),    \
        acc[m][3], 0, 0, 0)

    CLUSTER(0, 7);
    CLUSTER(1, 6);
    CLUSTER(2, 5);
    CLUSTER(3, 4);
    CLUSTER(4, 3);
    CLUSTER(5, 2);
    CLUSTER(6, 1);
    CLUSTER(7, 0);
#undef CLUSTER
    __builtin_amdgcn_s_setprio(0);
    __builtin_amdgcn_sched_barrier(0);
    FENCE(); __builtin_amdgcn_s_barrier(); FENCE();
  }
#undef STAGE_A
#undef STAGE_B

  const int rowBase = bm * 256 + wr * 128 + lg * 4;
  const int colBase = bn * 256 + wc * 64 + lr;
  if (bn < nFtiles) {
#pragma unroll
    for (int n = 0; n < 4; ++n) {
      int col = colBase + n * 16;
      float bv = bias[col];
#pragma unroll
      for (int m = 0; m < 8; ++m) {
        int row = rowBase + m * 16;
#pragma unroll
        for (int j = 0; j < 4; ++j)
          outF[(size_t)(row + j) * NF + col] = acc[m][n][j] + bv;
      }
    }
  } else {
    const int colB = colBase - nFtiles * 256;
#pragma unroll
    for (int n = 0; n < 4; ++n) {
      int col = colB + n * 16;
      float bv = bias[colBase + n * 16];
#pragma unroll
      for (int m = 0; m < 8; ++m) {
        int row = rowBase + m * 16;
#pragma unroll
        for (int j = 0; j < 4; ++j)
          outB[(size_t)(row + j) * NB + col] = f2bf(fmaxf(acc[m][n][j] + bv, 0.f));
      }
    }
  }
}

// ---------------------------------------------------------------------------
// GEMV head: out[m] = sum_k A[m*lda+k]*w[k] + b.  One wave per row.
// ---------------------------------------------------------------------------
__global__ void gemv_kernel(const unsigned short* __restrict__ Abf,
                            const float* __restrict__ wvec,
                            const float* __restrict__ bias,
                            float* __restrict__ out, int K, int lda) {
  int row  = blockIdx.x * 4 + (threadIdx.x >> 6);
  int lane = threadIdx.x & 63;
  const unsigned short* ap = Abf + (size_t)row * lda;
  float s = 0.f;
  for (int k = lane * 8; k < K; k += 512) {
    u16x8 v = *(const u16x8*)(ap + k);
#pragma unroll
    for (int j = 0; j < 8; ++j) s += bf2f(v[j]) * wvec[k + j];
  }
#pragma unroll
  for (int off = 32; off; off >>= 1) s += __shfl_down(s, off);
  if (lane == 0) out[row] = s + bias[0];
}

// ---------------------------------------------------------------------------
extern "C" void kernel_launch(void* const* d_in, const int* in_sizes, int n_in,
                              void* d_out, int out_size, void* d_ws, size_t ws_size,
                              hipStream_t stream) {
  const float* x     = (const float*)d_in[0];
  const float* field = (const float*)d_in[1];
  const float* fw1   = (const float*)d_in[2];
  const float* fb1   = (const float*)d_in[3];
  const float* fw2   = (const float*)d_in[4];
  const float* fb2   = (const float*)d_in[5];
  const float* ww1   = (const float*)d_in[6];
  const float* wb1   = (const float*)d_in[7];
  const float* ww2   = (const float*)d_in[8];
  const float* wb2   = (const float*)d_in[9];
  const float* ww3   = (const float*)d_in[10];
  const float* wb3   = (const float*)d_in[11];
  const float* tw1   = (const float*)d_in[12];
  const float* tb1   = (const float*)d_in[13];
  const float* tw2   = (const float*)d_in[14];
  const float* tb2   = (const float*)d_in[15];

  const int M = 16384;
  float* outF    = (float*)d_out;                  // field_output [16384,4096]
  float* outWil  = outF + (size_t)M * 4096;
  float* outTop  = outWil + M;
  float* outPlaq = outTop + M;

  char* ws = (char*)d_ws;
  const size_t MB = 1048576;
  unsigned short* hbuf    = (unsigned short*)(ws);              // [16384,2048] 64MB
  unsigned short* catbuf  = (unsigned short*)(ws + 64  * MB);   // [16384,4096] 128MB (w1|t)
  unsigned short* catT    = (unsigned short*)(ws + 192 * MB);   // [4096,4096]  32MB (dead after GEMM_W)
  unsigned short* w2buf   = (unsigned short*)(ws + 192 * MB);   // [16384,1024] 32MB (reuses catT)
  unsigned short* fw2T    = (unsigned short*)(ws + 224 * MB);   // [4096,2048]  16MB  \ contiguous =
  unsigned short* W2catT  = (unsigned short*)(ws + 240 * MB);   // [4096,2048]  16MB  / BTcat [8192,2048]
  unsigned short* BTcat   = fw2T;
  unsigned short* fw2bf   = (unsigned short*)(ws + 256 * MB);   // [2048,4096]  16MB
  unsigned short* ww2T    = (unsigned short*)(ws + 272 * MB);   // [1024,2048]  4MB
  float*          biascat = (float*)(ws + 276 * MB);            // [8192] 32KB

  const int SMEM = 65536;   // ring-2 LDS -> 2 blocks/CU
  (void)hipFuncSetAttribute((const void*)gemm256_kernel,
                            hipFuncAttributeMaxDynamicSharedMemorySize, SMEM);

  // independent prep
  hipLaunchKernelGGL(plaq_kernel, dim3(1), dim3(64), 0, stream, x, field, outPlaq);
  hipLaunchKernelGGL(fc1_kernel, dim3(16384), dim3(256), 0, stream, x, fw1, fb1, hbuf);
  hipLaunchKernelGGL(transpose_bf16_kernel, dim3(128, 64), dim3(32, 8), 0, stream,
                     fw2, fw2T, 2048, 4096);
  hipLaunchKernelGGL(cast_bf16_kernel, dim3(4096), dim3(256), 0, stream, fw2, fw2bf);
  hipLaunchKernelGGL(transpose_bf16_kernel, dim3(64, 128), dim3(32, 8), 0, stream,
                     ww1, catT, 4096, 2048);
  hipLaunchKernelGGL(transpose_bf16_kernel, dim3(64, 128), dim3(32, 8), 0, stream,
                     tw1, catT + (size_t)2048 * 4096, 4096, 2048);
  hipLaunchKernelGGL(transpose_bf16_kernel, dim3(32, 64), dim3(32, 8), 0, stream,
                     ww2, ww2T, 2048, 1024);
  hipLaunchKernelGGL(biascat_kernel, dim3(2048), dim3(256), 0, stream,
                     catT, fb2, wb1, tb1, biascat);

  // W2catT[n][k] = sum_j catT[n][j] * fw2bf[k][j]   (M=4096, N=2048, K=4096)
  hipLaunchKernelGGL(gemm128_kernel, dim3(32, 16), dim3(256), 0, stream,
                     catT, fw2bf, W2catT, 2048, 4096);

  // fused: C = h @ [fw2 | W2cat] + biascat   (M=16384, N=8192, K=2048)
  //   bn<16: field_output f32 -> outF;  bn>=16: relu bf16 -> catbuf
  hipLaunchKernelGGL(gemm256_kernel, dim3(64 * 32), dim3(512), SMEM, stream,
                     hbuf, BTcat, biascat, outF, catbuf,
                     2048, 2048, 4096, 4096, 16, 64);

  // w2 = relu(w1 @ ww2 + wb2)   (A = catbuf cols 0..2047, lda 4096)
  hipLaunchKernelGGL(gemm256_kernel, dim3(64 * 4), dim3(512), SMEM, stream,
                     catbuf, ww2T, wb2, (float*)nullptr, w2buf,
                     4096, 2048, 0, 1024, 0, 64);

  // heads
  hipLaunchKernelGGL(gemv_kernel, dim3(4096), dim3(256), 0, stream,
                     w2buf, ww3, wb3, outWil, 1024, 1024);
  hipLaunchKernelGGL(gemv_kernel, dim3(4096), dim3(256), 0, stream,
                     catbuf + 2048, tw2, tb2, outTop, 2048, 4096);

  (void)in_sizes; (void)n_in; (void)out_size; (void)ws_size;
}

// Round 7
// 3043.876 us; speedup vs baseline: 2.3088x; 2.3088x over previous
//
#include <hip/hip_runtime.h>

#define L 10

using bf16x8 = __attribute__((ext_vector_type(8))) __bf16;
using u16x8  = __attribute__((ext_vector_type(8))) unsigned short;
using f32x4  = __attribute__((ext_vector_type(4))) float;

__device__ __forceinline__ unsigned short f2bf(float f) {
  unsigned int u = __float_as_uint(f);
  u += 0x7FFFu + ((u >> 16) & 1u);          // RNE
  return (unsigned short)(u >> 16);
}
__device__ __forceinline__ float bf2f(unsigned short h) {
  return __uint_as_float(((unsigned int)h) << 16);
}

// ---------------------------------------------------------------------------
// Plaquette: single thread, exact fp32, matching JAX trunc-cast + python mod.
// ---------------------------------------------------------------------------
__global__ void plaq_kernel(const float* __restrict__ x,
                            const float* __restrict__ field,
                            float* __restrict__ out) {
  if (threadIdx.x != 0 || blockIdx.x != 0) return;
  int c[4];
#pragma unroll
  for (int i = 0; i < 4; ++i) {
    int v = (int)x[i];
    v %= L; if (v < 0) v += L;
    c[i] = v;
  }
  float S = 0.f;
  for (int mu = 0; mu < 4; ++mu)
    for (int nu = mu + 1; nu < 4; ++nu) {
      int p[4] = {c[0], c[1], c[2], c[3]};
      float l1 = field[((p[0]*L + p[1])*L + p[2])*4 + mu];
      p[mu] = (p[mu] + 1) % L;
      float l2 = field[((p[0]*L + p[1])*L + p[2])*4 + nu];
      p[nu] = (p[nu] + 1) % L;
      float l3 = field[((p[0]*L + p[1])*L + p[2])*4 + mu];
      float l4 = field[((c[0]*L + c[1])*L + c[2])*4 + nu];
      S += l1 + l2 - l3 - l4;
    }
  out[0] = expf(S);
}

// ---------------------------------------------------------------------------
// fc1: h = relu(x[16384,4] @ fw1[4,2048] + fb1) -> bf16.
// ---------------------------------------------------------------------------
__global__ void fc1_kernel(const float* __restrict__ x,
                           const float* __restrict__ fw1,
                           const float* __restrict__ fb1,
                           unsigned short* __restrict__ h) {
  const int N = 2048;
  int idx = blockIdx.x * blockDim.x + threadIdx.x;
  int m  = idx >> 8;
  int n0 = (idx & 255) * 8;
  float4 xv = *(const float4*)(x + (size_t)m * 4);
  unsigned short o[8];
#pragma unroll
  for (int j = 0; j < 8; ++j) {
    int n = n0 + j;
    float s = fb1[n] + xv.x * fw1[n] + xv.y * fw1[N + n]
                     + xv.z * fw1[2*N + n] + xv.w * fw1[3*N + n];
    o[j] = f2bf(fmaxf(s, 0.f));
  }
  *(u16x8*)(h + (size_t)m * N + n0) = *(const u16x8*)o;
}

// ---------------------------------------------------------------------------
// Weight transpose+convert: W[K][N] f32 -> WT[N][K] bf16.
// ---------------------------------------------------------------------------
__global__ void transpose_bf16_kernel(const float* __restrict__ W,
                                      unsigned short* __restrict__ WT,
                                      int K, int N) {
  __shared__ float tile[32][33];
  int n0 = blockIdx.x * 32, k0 = blockIdx.y * 32;
  int tx = threadIdx.x, ty = threadIdx.y;   // 32 x 8
#pragma unroll
  for (int i = 0; i < 32; i += 8)
    tile[ty + i][tx] = W[(size_t)(k0 + ty + i) * N + n0 + tx];
  __syncthreads();
#pragma unroll
  for (int i = 0; i < 32; i += 8)
    WT[(size_t)(n0 + ty + i) * K + k0 + tx] = f2bf(tile[tx][ty + i]);
}

// ---------------------------------------------------------------------------
// Elementwise f32 -> bf16 cast (natural layout), 8 elems/thread.
// ---------------------------------------------------------------------------
__global__ void cast_bf16_kernel(const float* __restrict__ in,
                                 unsigned short* __restrict__ out) {
  size_t i = ((size_t)blockIdx.x * blockDim.x + threadIdx.x) * 8;
  unsigned short o[8];
#pragma unroll
  for (int j = 0; j < 8; ++j) o[j] = f2bf(in[i + j]);
  *(u16x8*)(out + i) = *(const u16x8*)o;
}

// ---------------------------------------------------------------------------
// biascat: out[0:4096] = fb2; out[4096+m] = (m<2048?wb1[m]:tb1[m-2048])
//                                + sum_j catT[m][j]*fb2[j]    (wave per row)
// ---------------------------------------------------------------------------
__global__ void biascat_kernel(const unsigned short* __restrict__ catT,
                               const float* __restrict__ fb2,
                               const float* __restrict__ wb1,
                               const float* __restrict__ tb1,
                               float* __restrict__ out) {
  int w    = blockIdx.x * 4 + (threadIdx.x >> 6);   // 0..8191
  int lane = threadIdx.x & 63;
  if (w < 4096) { if (lane == 0) out[w] = fb2[w]; return; }
  int m = w - 4096;
  const unsigned short* row = catT + (size_t)m * 4096;
  float s = 0.f;
  for (int k = lane * 8; k < 4096; k += 512) {
    u16x8 v = *(const u16x8*)(row + k);
#pragma unroll
    for (int j = 0; j < 8; ++j) s += bf2f(v[j]) * fb2[k + j];
  }
#pragma unroll
  for (int off = 32; off; off >>= 1) s += __shfl_down(s, off);
  if (lane == 0) out[w] = s + (m < 2048 ? wb1[m] : tb1[m - 2048]);
}

// ---------------------------------------------------------------------------
// 128x128 bf16 MFMA GEMM (2 blocks/CU) for the weight product
// W2catT = (fw2 @ [ww1|tw1])^T.  C[m][n] = sum_k A[m,k]*BT[n,k], bf16 out.
// ---------------------------------------------------------------------------
__global__ __launch_bounds__(256, 2)
void gemm128_kernel(const unsigned short* __restrict__ A,
                    const unsigned short* __restrict__ BT,
                    unsigned short* __restrict__ outB,
                    int N, int K) {
  constexpr int BK = 64;
  __shared__ unsigned short As[128 * BK];
  __shared__ unsigned short Bs[128 * BK];

  const int bm = blockIdx.x, bn = blockIdx.y;
  const int tid = threadIdx.x;
  const int wid = tid >> 6, lane = tid & 63;
  const int wr = wid >> 1, wc = wid & 1;
  const int lr = lane & 15, lg = lane >> 4;

  f32x4 acc[4][4];
#pragma unroll
  for (int m = 0; m < 4; ++m)
#pragma unroll
    for (int n = 0; n < 4; ++n) acc[m][n] = (f32x4)0.f;

  const int srow = wid * 32 + (lane >> 3);
  const int scol = (lane & 7) * 8;
  const unsigned short* Ag = A  + (size_t)(bm * 128 + srow) * K + scol;
  const unsigned short* Bg = BT + (size_t)(bn * 128 + srow) * K + scol;

  for (int kt = 0; kt < K; kt += BK) {
#pragma unroll
    for (int i = 0; i < 4; ++i) {
      __builtin_amdgcn_global_load_lds(
          (const __attribute__((address_space(1))) unsigned int*)(Ag + (size_t)i * 8 * K + kt),
          (__attribute__((address_space(3))) unsigned int*)&As[wid * 2048 + i * 512],
          16, 0, 0);
      __builtin_amdgcn_global_load_lds(
          (const __attribute__((address_space(1))) unsigned int*)(Bg + (size_t)i * 8 * K + kt),
          (__attribute__((address_space(3))) unsigned int*)&Bs[wid * 2048 + i * 512],
          16, 0, 0);
    }
    __syncthreads();
#pragma unroll
    for (int kk = 0; kk < 2; ++kk) {
      u16x8 af[4], bf[4];
#pragma unroll
      for (int m = 0; m < 4; ++m)
        af[m] = *(const u16x8*)&As[(wr * 64 + m * 16 + lr) * BK + kk * 32 + lg * 8];
#pragma unroll
      for (int n = 0; n < 4; ++n)
        bf[n] = *(const u16x8*)&Bs[(wc * 64 + n * 16 + lr) * BK + kk * 32 + lg * 8];
#pragma unroll
      for (int m = 0; m < 4; ++m)
#pragma unroll
        for (int n = 0; n < 4; ++n)
          acc[m][n] = __builtin_amdgcn_mfma_f32_16x16x32_bf16(
              __builtin_bit_cast(bf16x8, af[m]),
              __builtin_bit_cast(bf16x8, bf[n]),
              acc[m][n], 0, 0, 0);
    }
    __syncthreads();
  }

  const int rowBase = bm * 128 + wr * 64 + lg * 4;
  const int colBase = bn * 128 + wc * 64 + lr;
#pragma unroll
  for (int n = 0; n < 4; ++n) {
    int col = colBase + n * 16;
#pragma unroll
    for (int m = 0; m < 4; ++m) {
      int row = rowBase + m * 16;
#pragma unroll
      for (int j = 0; j < 4; ++j)
        outB[(size_t)(row + j) * N + col] = f2bf(acc[m][n][j]);
    }
  }
}

// ---------------------------------------------------------------------------
// 256x256 bf16 MFMA GEMM — m201-style 8-phase schedule. BK=64, 2 K-tiles per
// iteration, 2 x 64KB LDS buffers (even tiles -> buf0, odd -> buf1), 8 waves
// (2Mx4N), per-wave 128x64 (acc 8x4). Read-ahead one phase with counted
// lgkmcnt(4/8); staging spread over phases into DEAD regions only; vmcnt
// gates (4/2) + barrier ONLY at phases 4 and 8. XOR swizzle (row&7 on 16B
// chunks of 128B rows) -> 2-way max on ds_read_b128 (free). T1 XCD swizzle.
// Split epilogue: bn<nFtiles -> f32 outF; else relu bf16 -> outB at col-4096.
// ---------------------------------------------------------------------------
#define GLL(gp, lp)                                                            \
  __builtin_amdgcn_global_load_lds(                                            \
      (const __attribute__((address_space(1))) unsigned int*)(gp),             \
      (__attribute__((address_space(3))) unsigned int*)(lp), 16, 0, 0)

#define DSREAD(dst, addr)                                                      \
  asm volatile("ds_read_b128 %0, %1" : "=v"(dst) : "v"(addr))

#define LGKM(n)                                                                \
  do { asm volatile("s_waitcnt lgkmcnt(" #n ")" ::: "memory");                 \
       __builtin_amdgcn_sched_barrier(0); } while (0)

#define VMC(n)  asm volatile("s_waitcnt vmcnt(" #n ")" ::: "memory")
#define FENCE() asm volatile("" ::: "memory")
#define BAR()   do { FENCE(); __builtin_amdgcn_s_barrier(); FENCE(); } while (0)

extern __shared__ char lds_raw[];

__global__ __launch_bounds__(512)
void gemm256_kernel(const unsigned short* __restrict__ A,
                    const unsigned short* __restrict__ BT,
                    const float* __restrict__ bias,
                    float* __restrict__ outF,
                    unsigned short* __restrict__ outB,
                    int lda, int K, int NF, int NB, int nFtiles, int gmx) {
  const int NI = K >> 7;                      // iterations (2 x K64 tiles each)

  // T1: bijective XCD swizzle, bm fastest
  const int nwg = gridDim.x;
  const int q = nwg >> 3, r = nwg & 7;
  const int xcd = blockIdx.x & 7, lid = blockIdx.x >> 3;
  const int wg2 = (xcd < r ? xcd * (q + 1) : r * (q + 1) + (xcd - r) * q) + lid;
  const int bm = wg2 % gmx, bn = wg2 / gmx;

  const int tid  = threadIdx.x;
  const int wid  = tid >> 6, lane = tid & 63;
  const int wr   = wid >> 2, wc = wid & 3;          // 2 x 4 waves
  const int lr   = lane & 15, lg = lane >> 4;

  // ---- staging: rows of 128B = 8 chunks of 16B; phys chunk = logical ^ (row&7)
  // thread t, load g: storage row = g*64 + (t>>3), phys chunk = t&7
  const int scol = ((tid & 7) ^ ((tid >> 3) & 7)) * 8;   // elems
  const unsigned short* aS = A  + (size_t)(bm * 256 + (tid >> 3)) * lda + scol;
  const unsigned short* bS = BT + (size_t)(bn * 256 + (tid >> 3)) * K  + scol;
  const size_t sA64 = (size_t)64 * lda, sB64 = (size_t)64 * K;

  // LDS buf layout: buf(t&1) at (t&1)<<16; A half h at h*16384; B at +32768.
#define STG_A(tile, half, g)                                                   \
  GLL(aS + (size_t)((half)*2 + (g)) * sA64 + (size_t)(tile) * 64,              \
      lds_raw + (((tile)&1) << 16) + (half)*16384 + (g)*8192 + tid*16)
#define STG_B(tile, half, g)                                                   \
  GLL(bS + (size_t)((half)*2 + (g)) * sB64 + (size_t)(tile) * 64,              \
      lds_raw + (((tile)&1) << 16) + 32768 + (half)*16384 + (g)*8192 + tid*16)
#define SHA(tile, half) do { STG_A(tile, half, 0); STG_A(tile, half, 1); } while (0)
#define SHB(tile, half) do { STG_B(tile, half, 0); STG_B(tile, half, 1); } while (0)

  // ---- read-side addresses: frag (m|n, kk) at row' * 128B + phys-chunk*16
  const unsigned ldsb = (unsigned)(uintptr_t)&lds_raw[0];
  const unsigned ck0  = (unsigned)(((lg)     ^ (lr & 7)) * 16);
  const unsigned ck1  = (unsigned)(((4 + lg) ^ (lr & 7)) * 16);
  const unsigned aB0  = ldsb + (unsigned)(wr * 16384 + lr * 128);
  const unsigned bB0  = ldsb + (unsigned)(32768 + (wc >> 1) * 16384 +
                                          (wc & 1) * 8192 + lr * 128);
#define RD_A(dst, buf, m, ck) DSREAD(dst, aB0 + ((buf) << 16) + (m)*2048 + (ck))
#define RD_B(dst, buf, n, ck) DSREAD(dst, bB0 + ((buf) << 16) + (n)*2048 + (ck))
#define R8(BS, AS, buf, ck) do {                                               \
    RD_B(BS[0], buf, 0, ck); RD_B(BS[1], buf, 1, ck);                          \
    RD_B(BS[2], buf, 2, ck); RD_B(BS[3], buf, 3, ck);                          \
    RD_A(AS[0], buf, 0, ck); RD_A(AS[1], buf, 1, ck);                          \
    RD_A(AS[2], buf, 2, ck); RD_A(AS[3], buf, 3, ck); } while (0)
#define R4(AS, buf, ck) do {                                                   \
    RD_A(AS[0], buf, 4, ck); RD_A(AS[1], buf, 5, ck);                          \
    RD_A(AS[2], buf, 6, ck); RD_A(AS[3], buf, 7, ck); } while (0)

  f32x4 acc[8][4];
#pragma unroll
  for (int m = 0; m < 8; ++m)
#pragma unroll
    for (int n = 0; n < 4; ++n) acc[m][n] = (f32x4)0.f;

#define QUAD(mb, AS, BS) do {                                                  \
    __builtin_amdgcn_s_setprio(1);                                             \
    _Pragma("unroll")                                                          \
    for (int _m = 0; _m < 4; ++_m)                                             \
      _Pragma("unroll")                                                        \
      for (int _n = 0; _n < 4; ++_n)                                           \
        acc[(mb) + _m][_n] = __builtin_amdgcn_mfma_f32_16x16x32_bf16(          \
            __builtin_bit_cast(bf16x8, AS[_m]),                                \
            __builtin_bit_cast(bf16x8, BS[_n]), acc[(mb) + _m][_n], 0, 0, 0);  \
    __builtin_amdgcn_s_setprio(0);                                             \
  } while (0)

  u16x8 bA[4], bX[4], aA[4], aX[4];

  // prologue: tile0 (8 loads) + tile1 Bh0 (2); gate tile0; read R1
  SHB(0, 0); SHB(0, 1); SHA(0, 0); SHA(0, 1);
  SHB(1, 0);
  VMC(2); BAR();
  R8(bA, aA, 0, ck0);                       // R1: b(t0,k0), a03(t0,k0)

  for (int i = 0; i < NI; ++i) {
    const int t1 = 2 * i + 1;
    const bool nx = (i + 1 < NI);
    // ph1: stage rest of t1 (buf1 fully dead); R2=a47(t0,k0); M1
    SHB(t1, 1); SHA(t1, 0); SHA(t1, 1);
    R4(aX, 0, ck0);
    LGKM(4); QUAD(0, aA, bA); BAR();
    // ph2: R3 = b'(t0,k1)+a03'(t0,k1); M2
    R8(bX, aA, 0, ck1);
    LGKM(8); QUAD(4, aX, bA); BAR();
    // ph3: R4 = a47'(t0,k1); M3
    R4(aX, 0, ck1);
    LGKM(4); QUAD(0, aA, bX); BAR();
    // ph4: stage B(t0+2) into buf0-B (dead after ph3); gate t1; R5; M4
    if (nx) { SHB(2 * i + 2, 0); SHB(2 * i + 2, 1); VMC(4); }
    else VMC(0);
    BAR();
    R8(bA, aA, 1, ck0);                     // R5: b(t1,k0), a03(t1,k0)
    LGKM(8); QUAD(4, aX, bX); BAR();
    // ph5: stage A(t0+2) into buf0-A (dead after ph4); R6 = a47(t1,k0); M5
    if (nx) { SHA(2 * i + 2, 0); SHA(2 * i + 2, 1); }
    R4(aX, 1, ck0);
    LGKM(4); QUAD(0, aA, bA); BAR();
    // ph6: R7 = b'(t1,k1)+a03'(t1,k1); M6
    R8(bX, aA, 1, ck1);
    LGKM(8); QUAD(4, aX, bA); BAR();
    // ph7: R8 = a47'(t1,k1); M7
    R4(aX, 1, ck1);
    LGKM(4); QUAD(0, aA, bX); BAR();
    // ph8: stage Bh0(t1+2) (buf1-B dead after ph7); gate t0+2; R1'; M8
    if (nx) {
      SHB(2 * i + 3, 0);
      VMC(2); BAR();
      R8(bA, aA, 0, ck0);                   // R1' for next iteration
      LGKM(8);
    } else {
      VMC(0); BAR();
      LGKM(0);
    }
    QUAD(4, aX, bX); BAR();
  }
#undef STG_A
#undef STG_B
#undef SHA
#undef SHB
#undef RD_A
#undef RD_B
#undef R8
#undef R4
#undef QUAD

  const int rowBase = bm * 256 + wr * 128 + lg * 4;
  const int colBase = bn * 256 + wc * 64 + lr;
  if (bn < nFtiles) {
#pragma unroll
    for (int n = 0; n < 4; ++n) {
      int col = colBase + n * 16;
      float bv = bias[col];
#pragma unroll
      for (int m = 0; m < 8; ++m) {
        int row = rowBase + m * 16;
#pragma unroll
        for (int j = 0; j < 4; ++j)
          outF[(size_t)(row + j) * NF + col] = acc[m][n][j] + bv;
      }
    }
  } else {
    const int colB = colBase - nFtiles * 256;
#pragma unroll
    for (int n = 0; n < 4; ++n) {
      int col = colB + n * 16;
      float bv = bias[colBase + n * 16];
#pragma unroll
      for (int m = 0; m < 8; ++m) {
        int row = rowBase + m * 16;
#pragma unroll
        for (int j = 0; j < 4; ++j)
          outB[(size_t)(row + j) * NB + col] = f2bf(fmaxf(acc[m][n][j] + bv, 0.f));
      }
    }
  }
}

// ---------------------------------------------------------------------------
// GEMV head: out[m] = sum_k A[m*lda+k]*w[k] + b.  One wave per row.
// ---------------------------------------------------------------------------
__global__ void gemv_kernel(const unsigned short* __restrict__ Abf,
                            const float* __restrict__ wvec,
                            const float* __restrict__ bias,
                            float* __restrict__ out, int K, int lda) {
  int row  = blockIdx.x * 4 + (threadIdx.x >> 6);
  int lane = threadIdx.x & 63;
  const unsigned short* ap = Abf + (size_t)row * lda;
  float s = 0.f;
  for (int k = lane * 8; k < K; k += 512) {
    u16x8 v = *(const u16x8*)(ap + k);
#pragma unroll
    for (int j = 0; j < 8; ++j) s += bf2f(v[j]) * wvec[k + j];
  }
#pragma unroll
  for (int off = 32; off; off >>= 1) s += __shfl_down(s, off);
  if (lane == 0) out[row] = s + bias[0];
}

// ---------------------------------------------------------------------------
extern "C" void kernel_launch(void* const* d_in, const int* in_sizes, int n_in,
                              void* d_out, int out_size, void* d_ws, size_t ws_size,
                              hipStream_t stream) {
  const float* x     = (const float*)d_in[0];
  const float* field = (const float*)d_in[1];
  const float* fw1   = (const float*)d_in[2];
  const float* fb1   = (const float*)d_in[3];
  const float* fw2   = (const float*)d_in[4];
  const float* fb2   = (const float*)d_in[5];
  const float* ww1   = (const float*)d_in[6];
  const float* wb1   = (const float*)d_in[7];
  const float* ww2   = (const float*)d_in[8];
  const float* wb2   = (const float*)d_in[9];
  const float* ww3   = (const float*)d_in[10];
  const float* wb3   = (const float*)d_in[11];
  const float* tw1   = (const float*)d_in[12];
  const float* tb1   = (const float*)d_in[13];
  const float* tw2   = (const float*)d_in[14];
  const float* tb2   = (const float*)d_in[15];

  const int M = 16384;
  float* outF    = (float*)d_out;                  // field_output [16384,4096]
  float* outWil  = outF + (size_t)M * 4096;
  float* outTop  = outWil + M;
  float* outPlaq = outTop + M;

  char* ws = (char*)d_ws;
  const size_t MB = 1048576;
  unsigned short* hbuf    = (unsigned short*)(ws);              // [16384,2048] 64MB
  unsigned short* catbuf  = (unsigned short*)(ws + 64  * MB);   // [16384,4096] 128MB (w1|t)
  unsigned short* catT    = (unsigned short*)(ws + 192 * MB);   // [4096,4096]  32MB (dead after GEMM_W)
  unsigned short* w2buf   = (unsigned short*)(ws + 192 * MB);   // [16384,1024] 32MB (reuses catT)
  unsigned short* fw2T    = (unsigned short*)(ws + 224 * MB);   // [4096,2048]  16MB  \ contiguous =
  unsigned short* W2catT  = (unsigned short*)(ws + 240 * MB);   // [4096,2048]  16MB  / BTcat [8192,2048]
  unsigned short* BTcat   = fw2T;
  unsigned short* fw2bf   = (unsigned short*)(ws + 256 * MB);   // [2048,4096]  16MB
  unsigned short* ww2T    = (unsigned short*)(ws + 272 * MB);   // [1024,2048]  4MB
  float*          biascat = (float*)(ws + 276 * MB);            // [8192] 32KB

  const int SMEM = 131072;   // 2 x 64KB K64-tile buffers
  (void)hipFuncSetAttribute((const void*)gemm256_kernel,
                            hipFuncAttributeMaxDynamicSharedMemorySize, SMEM);

  // independent prep
  hipLaunchKernelGGL(plaq_kernel, dim3(1), dim3(64), 0, stream, x, field, outPlaq);
  hipLaunchKernelGGL(fc1_kernel, dim3(16384), dim3(256), 0, stream, x, fw1, fb1, hbuf);
  hipLaunchKernelGGL(transpose_bf16_kernel, dim3(128, 64), dim3(32, 8), 0, stream,
                     fw2, fw2T, 2048, 4096);
  hipLaunchKernelGGL(cast_bf16_kernel, dim3(4096), dim3(256), 0, stream, fw2, fw2bf);
  hipLaunchKernelGGL(transpose_bf16_kernel, dim3(64, 128), dim3(32, 8), 0, stream,
                     ww1, catT, 4096, 2048);
  hipLaunchKernelGGL(transpose_bf16_kernel, dim3(64, 128), dim3(32, 8), 0, stream,
                     tw1, catT + (size_t)2048 * 4096, 4096, 2048);
  hipLaunchKernelGGL(transpose_bf16_kernel, dim3(32, 64), dim3(32, 8), 0, stream,
                     ww2, ww2T, 2048, 1024);
  hipLaunchKernelGGL(biascat_kernel, dim3(2048), dim3(256), 0, stream,
                     catT, fb2, wb1, tb1, biascat);

  // W2catT[n][k] = sum_j catT[n][j] * fw2bf[k][j]   (M=4096, N=2048, K=4096)
  hipLaunchKernelGGL(gemm128_kernel, dim3(32, 16), dim3(256), 0, stream,
                     catT, fw2bf, W2catT, 2048, 4096);

  // fused: C = h @ [fw2 | W2cat] + biascat   (M=16384, N=8192, K=2048)
  //   bn<16: field_output f32 -> outF;  bn>=16: relu bf16 -> catbuf
  hipLaunchKernelGGL(gemm256_kernel, dim3(64 * 32), dim3(512), SMEM, stream,
                     hbuf, BTcat, biascat, outF, catbuf,
                     2048, 2048, 4096, 4096, 16, 64);

  // w2 = relu(w1 @ ww2 + wb2)   (A = catbuf cols 0..2047, lda 4096)
  hipLaunchKernelGGL(gemm256_kernel, dim3(64 * 4), dim3(512), SMEM, stream,
                     catbuf, ww2T, wb2, (float*)nullptr, w2buf,
                     4096, 2048, 0, 1024, 0, 64);

  // heads
  hipLaunchKernelGGL(gemv_kernel, dim3(4096), dim3(256), 0, stream,
                     w2buf, ww3, wb3, outWil, 1024, 1024);
  hipLaunchKernelGGL(gemv_kernel, dim3(4096), dim3(256), 0, stream,
                     catbuf + 2048, tw2, tb2, outTop, 2048, 4096);

  (void)in_sizes; (void)n_in; (void)out_size; (void)ws_size;
}

// Round 8
// 977.003 us; speedup vs baseline: 7.1932x; 3.1155x over previous
//
#include <hip/hip_runtime.h>

#define L 10

using bf16x8 = __attribute__((ext_vector_type(8))) __bf16;
using u16x8  = __attribute__((ext_vector_type(8))) unsigned short;
using f32x4  = __attribute__((ext_vector_type(4))) float;

__device__ __forceinline__ unsigned short f2bf(float f) {
  unsigned int u = __float_as_uint(f);
  u += 0x7FFFu + ((u >> 16) & 1u);          // RNE
  return (unsigned short)(u >> 16);
}
__device__ __forceinline__ float bf2f(unsigned short h) {
  return __uint_as_float(((unsigned int)h) << 16);
}

// ---------------------------------------------------------------------------
// Plaquette: single thread, exact fp32, matching JAX trunc-cast + python mod.
// ---------------------------------------------------------------------------
__global__ void plaq_kernel(const float* __restrict__ x,
                            const float* __restrict__ field,
                            float* __restrict__ out) {
  if (threadIdx.x != 0 || blockIdx.x != 0) return;
  int c[4];
#pragma unroll
  for (int i = 0; i < 4; ++i) {
    int v = (int)x[i];
    v %= L; if (v < 0) v += L;
    c[i] = v;
  }
  float S = 0.f;
  for (int mu = 0; mu < 4; ++mu)
    for (int nu = mu + 1; nu < 4; ++nu) {
      int p[4] = {c[0], c[1], c[2], c[3]};
      float l1 = field[((p[0]*L + p[1])*L + p[2])*4 + mu];
      p[mu] = (p[mu] + 1) % L;
      float l2 = field[((p[0]*L + p[1])*L + p[2])*4 + nu];
      p[nu] = (p[nu] + 1) % L;
      float l3 = field[((p[0]*L + p[1])*L + p[2])*4 + mu];
      float l4 = field[((c[0]*L + c[1])*L + c[2])*4 + nu];
      S += l1 + l2 - l3 - l4;
    }
  out[0] = expf(S);
}

// ---------------------------------------------------------------------------
// fc1: h = relu(x[16384,4] @ fw1[4,2048] + fb1) -> bf16.
// ---------------------------------------------------------------------------
__global__ void fc1_kernel(const float* __restrict__ x,
                           const float* __restrict__ fw1,
                           const float* __restrict__ fb1,
                           unsigned short* __restrict__ h) {
  const int N = 2048;
  int idx = blockIdx.x * blockDim.x + threadIdx.x;
  int m  = idx >> 8;
  int n0 = (idx & 255) * 8;
  float4 xv = *(const float4*)(x + (size_t)m * 4);
  unsigned short o[8];
#pragma unroll
  for (int j = 0; j < 8; ++j) {
    int n = n0 + j;
    float s = fb1[n] + xv.x * fw1[n] + xv.y * fw1[N + n]
                     + xv.z * fw1[2*N + n] + xv.w * fw1[3*N + n];
    o[j] = f2bf(fmaxf(s, 0.f));
  }
  *(u16x8*)(h + (size_t)m * N + n0) = *(const u16x8*)o;
}

// ---------------------------------------------------------------------------
// Weight transpose+convert: W[K][N] f32 -> WT[N][K] bf16.
// ---------------------------------------------------------------------------
__global__ void transpose_bf16_kernel(const float* __restrict__ W,
                                      unsigned short* __restrict__ WT,
                                      int K, int N) {
  __shared__ float tile[32][33];
  int n0 = blockIdx.x * 32, k0 = blockIdx.y * 32;
  int tx = threadIdx.x, ty = threadIdx.y;   // 32 x 8
#pragma unroll
  for (int i = 0; i < 32; i += 8)
    tile[ty + i][tx] = W[(size_t)(k0 + ty + i) * N + n0 + tx];
  __syncthreads();
#pragma unroll
  for (int i = 0; i < 32; i += 8)
    WT[(size_t)(n0 + ty + i) * K + k0 + tx] = f2bf(tile[tx][ty + i]);
}

// ---------------------------------------------------------------------------
// Elementwise f32 -> bf16 cast (natural layout), 8 elems/thread.
// ---------------------------------------------------------------------------
__global__ void cast_bf16_kernel(const float* __restrict__ in,
                                 unsigned short* __restrict__ out) {
  size_t i = ((size_t)blockIdx.x * blockDim.x + threadIdx.x) * 8;
  unsigned short o[8];
#pragma unroll
  for (int j = 0; j < 8; ++j) o[j] = f2bf(in[i + j]);
  *(u16x8*)(out + i) = *(const u16x8*)o;
}

// ---------------------------------------------------------------------------
// biascat: out[0:4096] = fb2; out[4096+m] = (m<2048?wb1[m]:tb1[m-2048])
//                                + sum_j catT[m][j]*fb2[j]    (wave per row)
// ---------------------------------------------------------------------------
__global__ void biascat_kernel(const unsigned short* __restrict__ catT,
                               const float* __restrict__ fb2,
                               const float* __restrict__ wb1,
                               const float* __restrict__ tb1,
                               float* __restrict__ out) {
  int w    = blockIdx.x * 4 + (threadIdx.x >> 6);   // 0..8191
  int lane = threadIdx.x & 63;
  if (w < 4096) { if (lane == 0) out[w] = fb2[w]; return; }
  int m = w - 4096;
  const unsigned short* row = catT + (size_t)m * 4096;
  float s = 0.f;
  for (int k = lane * 8; k < 4096; k += 512) {
    u16x8 v = *(const u16x8*)(row + k);
#pragma unroll
    for (int j = 0; j < 8; ++j) s += bf2f(v[j]) * fb2[k + j];
  }
#pragma unroll
  for (int off = 32; off; off >>= 1) s += __shfl_down(s, off);
  if (lane == 0) out[w] = s + (m < 2048 ? wb1[m] : tb1[m - 2048]);
}

// ---------------------------------------------------------------------------
// 128x128 bf16 MFMA GEMM (2 blocks/CU) for the weight product
// W2catT = (fw2 @ [ww1|tw1])^T.  C[m][n] = sum_k A[m,k]*BT[n,k], bf16 out.
// ---------------------------------------------------------------------------
__global__ __launch_bounds__(256, 2)
void gemm128_kernel(const unsigned short* __restrict__ A,
                    const unsigned short* __restrict__ BT,
                    unsigned short* __restrict__ outB,
                    int N, int K) {
  constexpr int BK = 64;
  __shared__ unsigned short As[128 * BK];
  __shared__ unsigned short Bs[128 * BK];

  const int bm = blockIdx.x, bn = blockIdx.y;
  const int tid = threadIdx.x;
  const int wid = tid >> 6, lane = tid & 63;
  const int wr = wid >> 1, wc = wid & 1;
  const int lr = lane & 15, lg = lane >> 4;

  f32x4 acc[4][4];
#pragma unroll
  for (int m = 0; m < 4; ++m)
#pragma unroll
    for (int n = 0; n < 4; ++n) acc[m][n] = (f32x4)0.f;

  const int srow = wid * 32 + (lane >> 3);
  const int scol = (lane & 7) * 8;
  const unsigned short* Ag = A  + (size_t)(bm * 128 + srow) * K + scol;
  const unsigned short* Bg = BT + (size_t)(bn * 128 + srow) * K + scol;

  for (int kt = 0; kt < K; kt += BK) {
#pragma unroll
    for (int i = 0; i < 4; ++i) {
      __builtin_amdgcn_global_load_lds(
          (const __attribute__((address_space(1))) unsigned int*)(Ag + (size_t)i * 8 * K + kt),
          (__attribute__((address_space(3))) unsigned int*)&As[wid * 2048 + i * 512],
          16, 0, 0);
      __builtin_amdgcn_global_load_lds(
          (const __attribute__((address_space(1))) unsigned int*)(Bg + (size_t)i * 8 * K + kt),
          (__attribute__((address_space(3))) unsigned int*)&Bs[wid * 2048 + i * 512],
          16, 0, 0);
    }
    __syncthreads();
#pragma unroll
    for (int kk = 0; kk < 2; ++kk) {
      u16x8 af[4], bf[4];
#pragma unroll
      for (int m = 0; m < 4; ++m)
        af[m] = *(const u16x8*)&As[(wr * 64 + m * 16 + lr) * BK + kk * 32 + lg * 8];
#pragma unroll
      for (int n = 0; n < 4; ++n)
        bf[n] = *(const u16x8*)&Bs[(wc * 64 + n * 16 + lr) * BK + kk * 32 + lg * 8];
#pragma unroll
      for (int m = 0; m < 4; ++m)
#pragma unroll
        for (int n = 0; n < 4; ++n)
          acc[m][n] = __builtin_amdgcn_mfma_f32_16x16x32_bf16(
              __builtin_bit_cast(bf16x8, af[m]),
              __builtin_bit_cast(bf16x8, bf[n]),
              acc[m][n], 0, 0, 0);
    }
    __syncthreads();
  }

  const int rowBase = bm * 128 + wr * 64 + lg * 4;
  const int colBase = bn * 128 + wc * 64 + lr;
#pragma unroll
  for (int n = 0; n < 4; ++n) {
    int col = colBase + n * 16;
#pragma unroll
    for (int m = 0; m < 4; ++m) {
      int row = rowBase + m * 16;
#pragma unroll
      for (int j = 0; j < 4; ++j)
        outB[(size_t)(row + j) * N + col] = f2bf(acc[m][n][j]);
    }
  }
}

// ---------------------------------------------------------------------------
// 256x256 bf16 MFMA GEMM, BK=32, ring-2 LDS (64KB). No min-waves bound: the
// allocator lands ~100-116 VGPR (r4/r5 evidence), so 2 blocks/CU co-reside
// and cover the per-tile vmcnt(0) drain (m114 cross-block overlap).
// Counted-lgkm read->MFMA interleave, zero-conflict XOR swizzle (T2),
// setprio (T5), bijective XCD swizzle (T1). Split epilogue:
//   bn <  nFtiles : C+bias -> f32 outF (no relu), row stride NF
//   bn >= nFtiles : relu(C+bias) -> bf16 outB at col-4096, row stride NB
// ---------------------------------------------------------------------------
#define GLL(gp, lp)                                                            \
  __builtin_amdgcn_global_load_lds(                                            \
      (const __attribute__((address_space(1))) unsigned int*)(gp),             \
      (__attribute__((address_space(3))) unsigned int*)(lp), 16, 0, 0)

#define DSREAD(dst, addr)                                                      \
  asm volatile("ds_read_b128 %0, %1" : "=v"(dst) : "v"(addr))

#define LGKM(n)                                                                \
  do { asm volatile("s_waitcnt lgkmcnt(" #n ")" ::: "memory");                 \
       __builtin_amdgcn_sched_barrier(0); } while (0)

#define FENCE() asm volatile("" ::: "memory")

extern __shared__ char lds_raw[];

__global__ __launch_bounds__(512)
void gemm256_kernel(const unsigned short* __restrict__ A,
                    const unsigned short* __restrict__ BT,
                    const float* __restrict__ bias,
                    float* __restrict__ outF,
                    unsigned short* __restrict__ outB,
                    int lda, int K, int NF, int NB, int nFtiles, int gmx) {
  const int NT = K >> 5;                      // K32 tiles

  // T1: bijective XCD swizzle, bm fastest
  const int nwg = gridDim.x;
  const int q = nwg >> 3, r = nwg & 7;
  const int xcd = blockIdx.x & 7, lid = blockIdx.x >> 3;
  const int wg2 = (xcd < r ? xcd * (q + 1) : r * (q + 1) + (xcd - r) * q) + lid;
  const int bm = wg2 % gmx, bn = wg2 / gmx;

  const int tid  = threadIdx.x;
  const int wid  = tid >> 6, lane = tid & 63;
  const int wr   = wid >> 2, wc = wid & 3;          // 2 x 4 waves
  const int lr   = lane & 15, lg = lane >> 4;

  // ---- staging (pre-swizzled global source, linear LDS dest) ----
  const int srow = tid >> 2;
  const int scol = ((tid & 3) ^ ((tid >> 3) & 3)) * 8;   // elems
  const unsigned short* agp0 = A  + (size_t)(bm * 256 + srow) * lda + scol;
  const unsigned short* agp1 = agp0 + (size_t)128 * lda;
  const unsigned short* bgp0 = BT + (size_t)(bn * 256 + srow) * K + scol;
  const unsigned short* bgp1 = bgp0 + (size_t)128 * K;

  // ---- read-side swizzled fragment offsets (0 bank conflicts) ----
  const int chunk = lg ^ ((lr >> 1) & 3);
  const unsigned ldsbase = (unsigned)(uintptr_t)&lds_raw[0];
  const unsigned aoff = (unsigned)((wr * 128 + lr) * 64 + chunk * 16);
  const unsigned boff = (unsigned)(16384 + (wc * 64 + lr) * 64 + chunk * 16);

  f32x4 acc[8][4];
#pragma unroll
  for (int m = 0; m < 8; ++m)
#pragma unroll
    for (int n = 0; n < 4; ++n) acc[m][n] = (f32x4)0.f;

#define STAGE_A(tt) do { unsigned so = (unsigned)(((tt) & 1) << 15);           \
    GLL(agp0 + (size_t)(tt) * 32, lds_raw + so + tid * 16);                    \
    GLL(agp1 + (size_t)(tt) * 32, lds_raw + so + 8192 + tid * 16); } while (0)
#define STAGE_B(tt) do { unsigned so = (unsigned)(((tt) & 1) << 15);           \
    GLL(bgp0 + (size_t)(tt) * 32, lds_raw + so + 16384 + tid * 16);            \
    GLL(bgp1 + (size_t)(tt) * 32, lds_raw + so + 24576 + tid * 16); } while (0)

  // prologue: tile 0 staged
  STAGE_A(0); STAGE_B(0);

  for (int t = 0; t < NT; ++t) {
    // drain: tile t landed. Co-resident block covers this stall (2 blk/CU).
    asm volatile("s_waitcnt vmcnt(0)" ::: "memory");
    FENCE(); __builtin_amdgcn_s_barrier(); FENCE();
    __builtin_amdgcn_sched_barrier(0);

    // stage next tile immediately: full-tile latency cover under this MFMA
    if (t + 1 < NT) { STAGE_A(t + 1); STAGE_B(t + 1); }

    const unsigned sbase = ldsbase + (unsigned)((t & 1) << 15);

    // issue reads in consumption order: b0-3 then a0-7 (in-order DS returns)
    u16x8 b[4], a[8];
    DSREAD(b[0], sbase + boff);
    DSREAD(b[1], sbase + boff + 1024);
    DSREAD(b[2], sbase + boff + 2048);
    DSREAD(b[3], sbase + boff + 3072);
    DSREAD(a[0], sbase + aoff);
    DSREAD(a[1], sbase + aoff + 1024);
    DSREAD(a[2], sbase + aoff + 2048);
    DSREAD(a[3], sbase + aoff + 3072);
    DSREAD(a[4], sbase + aoff + 4096);
    DSREAD(a[5], sbase + aoff + 5120);
    DSREAD(a[6], sbase + aoff + 6144);
    DSREAD(a[7], sbase + aoff + 7168);

    // 8 clusters: counted lgkm gate -> 4 MFMA; LDS serves ahead under MFMA.
    // cluster 7's LGKM(0) retires all reads of this slot before the trailing
    // barrier, so the next iteration's STAGE into it is race-free.
    __builtin_amdgcn_s_setprio(1);
#define CLUSTER(m, g)                                                          \
    LGKM(g);                                                                   \
    acc[m][0] = __builtin_amdgcn_mfma_f32_16x16x32_bf16(                       \
        __builtin_bit_cast(bf16x8, a[m]), __builtin_bit_cast(bf16x8, b[0]),    \
        acc[m][0], 0, 0, 0);                                                   \
    acc[m][1] = __builtin_amdgcn_mfma_f32_16x16x32_bf16(                       \
        __builtin_bit_cast(bf16x8, a[m]), __builtin_bit_cast(bf16x8, b[1]),    \
        acc[m][1], 0, 0, 0);                                                   \
    acc[m][2] = __builtin_amdgcn_mfma_f32_16x16x32_bf16(                       \
        __builtin_bit_cast(bf16x8, a[m]), __builtin_bit_cast(bf16x8, b[2]),    \
        acc[m][2], 0, 0, 0);                                                   \
    acc[m][3] = __builtin_amdgcn_mfma_f32_16x16x32_bf16(                       \
        __builtin_bit_cast(bf16x8, a[m]), __builtin_bit_cast(bf16x8, b[3]),    \
        acc[m][3], 0, 0, 0)

    CLUSTER(0, 7);
    CLUSTER(1, 6);
    CLUSTER(2, 5);
    CLUSTER(3, 4);
    CLUSTER(4, 3);
    CLUSTER(5, 2);
    CLUSTER(6, 1);
    CLUSTER(7, 0);
#undef CLUSTER
    __builtin_amdgcn_s_setprio(0);
    __builtin_amdgcn_sched_barrier(0);
    FENCE(); __builtin_amdgcn_s_barrier(); FENCE();
  }
#undef STAGE_A
#undef STAGE_B

  const int rowBase = bm * 256 + wr * 128 + lg * 4;
  const int colBase = bn * 256 + wc * 64 + lr;
  if (bn < nFtiles) {
#pragma unroll
    for (int n = 0; n < 4; ++n) {
      int col = colBase + n * 16;
      float bv = bias[col];
#pragma unroll
      for (int m = 0; m < 8; ++m) {
        int row = rowBase + m * 16;
#pragma unroll
        for (int j = 0; j < 4; ++j)
          outF[(size_t)(row + j) * NF + col] = acc[m][n][j] + bv;
      }
    }
  } else {
    const int colB = colBase - nFtiles * 256;
#pragma unroll
    for (int n = 0; n < 4; ++n) {
      int col = colB + n * 16;
      float bv = bias[colBase + n * 16];
#pragma unroll
      for (int m = 0; m < 8; ++m) {
        int row = rowBase + m * 16;
#pragma unroll
        for (int j = 0; j < 4; ++j)
          outB[(size_t)(row + j) * NB + col] = f2bf(fmaxf(acc[m][n][j] + bv, 0.f));
      }
    }
  }
}

// ---------------------------------------------------------------------------
// GEMV head: out[m] = sum_k A[m*lda+k]*w[k] + b.  One wave per row.
// ---------------------------------------------------------------------------
__global__ void gemv_kernel(const unsigned short* __restrict__ Abf,
                            const float* __restrict__ wvec,
                            const float* __restrict__ bias,
                            float* __restrict__ out, int K, int lda) {
  int row  = blockIdx.x * 4 + (threadIdx.x >> 6);
  int lane = threadIdx.x & 63;
  const unsigned short* ap = Abf + (size_t)row * lda;
  float s = 0.f;
  for (int k = lane * 8; k < K; k += 512) {
    u16x8 v = *(const u16x8*)(ap + k);
#pragma unroll
    for (int j = 0; j < 8; ++j) s += bf2f(v[j]) * wvec[k + j];
  }
#pragma unroll
  for (int off = 32; off; off >>= 1) s += __shfl_down(s, off);
  if (lane == 0) out[row] = s + bias[0];
}

// ---------------------------------------------------------------------------
extern "C" void kernel_launch(void* const* d_in, const int* in_sizes, int n_in,
                              void* d_out, int out_size, void* d_ws, size_t ws_size,
                              hipStream_t stream) {
  const float* x     = (const float*)d_in[0];
  const float* field = (const float*)d_in[1];
  const float* fw1   = (const float*)d_in[2];
  const float* fb1   = (const float*)d_in[3];
  const float* fw2   = (const float*)d_in[4];
  const float* fb2   = (const float*)d_in[5];
  const float* ww1   = (const float*)d_in[6];
  const float* wb1   = (const float*)d_in[7];
  const float* ww2   = (const float*)d_in[8];
  const float* wb2   = (const float*)d_in[9];
  const float* ww3   = (const float*)d_in[10];
  const float* wb3   = (const float*)d_in[11];
  const float* tw1   = (const float*)d_in[12];
  const float* tb1   = (const float*)d_in[13];
  const float* tw2   = (const float*)d_in[14];
  const float* tb2   = (const float*)d_in[15];

  const int M = 16384;
  float* outF    = (float*)d_out;                  // field_output [16384,4096]
  float* outWil  = outF + (size_t)M * 4096;
  float* outTop  = outWil + M;
  float* outPlaq = outTop + M;

  char* ws = (char*)d_ws;
  const size_t MB = 1048576;
  unsigned short* hbuf    = (unsigned short*)(ws);              // [16384,2048] 64MB
  unsigned short* catbuf  = (unsigned short*)(ws + 64  * MB);   // [16384,4096] 128MB (w1|t)
  unsigned short* catT    = (unsigned short*)(ws + 192 * MB);   // [4096,4096]  32MB (dead after GEMM_W)
  unsigned short* w2buf   = (unsigned short*)(ws + 192 * MB);   // [16384,1024] 32MB (reuses catT)
  unsigned short* fw2T    = (unsigned short*)(ws + 224 * MB);   // [4096,2048]  16MB  \ contiguous =
  unsigned short* W2catT  = (unsigned short*)(ws + 240 * MB);   // [4096,2048]  16MB  / BTcat [8192,2048]
  unsigned short* BTcat   = fw2T;
  unsigned short* fw2bf   = (unsigned short*)(ws + 256 * MB);   // [2048,4096]  16MB
  unsigned short* ww2T    = (unsigned short*)(ws + 272 * MB);   // [1024,2048]  4MB
  float*          biascat = (float*)(ws + 276 * MB);            // [8192] 32KB

  const int SMEM = 65536;   // ring-2 LDS -> 2 blocks/CU (VGPR permitting)
  (void)hipFuncSetAttribute((const void*)gemm256_kernel,
                            hipFuncAttributeMaxDynamicSharedMemorySize, SMEM);

  // independent prep
  hipLaunchKernelGGL(plaq_kernel, dim3(1), dim3(64), 0, stream, x, field, outPlaq);
  hipLaunchKernelGGL(fc1_kernel, dim3(16384), dim3(256), 0, stream, x, fw1, fb1, hbuf);
  hipLaunchKernelGGL(transpose_bf16_kernel, dim3(128, 64), dim3(32, 8), 0, stream,
                     fw2, fw2T, 2048, 4096);
  hipLaunchKernelGGL(cast_bf16_kernel, dim3(4096), dim3(256), 0, stream, fw2, fw2bf);
  hipLaunchKernelGGL(transpose_bf16_kernel, dim3(64, 128), dim3(32, 8), 0, stream,
                     ww1, catT, 4096, 2048);
  hipLaunchKernelGGL(transpose_bf16_kernel, dim3(64, 128), dim3(32, 8), 0, stream,
                     tw1, catT + (size_t)2048 * 4096, 4096, 2048);
  hipLaunchKernelGGL(transpose_bf16_kernel, dim3(32, 64), dim3(32, 8), 0, stream,
                     ww2, ww2T, 2048, 1024);
  hipLaunchKernelGGL(biascat_kernel, dim3(2048), dim3(256), 0, stream,
                     catT, fb2, wb1, tb1, biascat);

  // W2catT[n][k] = sum_j catT[n][j] * fw2bf[k][j]   (M=4096, N=2048, K=4096)
  hipLaunchKernelGGL(gemm128_kernel, dim3(32, 16), dim3(256), 0, stream,
                     catT, fw2bf, W2catT, 2048, 4096);

  // fused: C = h @ [fw2 | W2cat] + biascat   (M=16384, N=8192, K=2048)
  //   bn<16: field_output f32 -> outF;  bn>=16: relu bf16 -> catbuf
  hipLaunchKernelGGL(gemm256_kernel, dim3(64 * 32), dim3(512), SMEM, stream,
                     hbuf, BTcat, biascat, outF, catbuf,
                     2048, 2048, 4096, 4096, 16, 64);

  // w2 = relu(w1 @ ww2 + wb2)   (A = catbuf cols 0..2047, lda 4096)
  hipLaunchKernelGGL(gemm256_kernel, dim3(64 * 4), dim3(512), SMEM, stream,
                     catbuf, ww2T, wb2, (float*)nullptr, w2buf,
                     4096, 2048, 0, 1024, 0, 64);

  // heads
  hipLaunchKernelGGL(gemv_kernel, dim3(4096), dim3(256), 0, stream,
                     w2buf, ww3, wb3, outWil, 1024, 1024);
  hipLaunchKernelGGL(gemv_kernel, dim3(4096), dim3(256), 0, stream,
                     catbuf + 2048, tw2, tb2, outTop, 2048, 4096);

  (void)in_sizes; (void)n_in; (void)out_size; (void)ws_size;
}

// Round 9
// 944.394 us; speedup vs baseline: 7.4415x; 1.0345x over previous
//
#include <hip/hip_runtime.h>

#define L 10

using bf16x8 = __attribute__((ext_vector_type(8))) __bf16;
using u16x8  = __attribute__((ext_vector_type(8))) unsigned short;
using f32x4  = __attribute__((ext_vector_type(4))) float;

__device__ __forceinline__ unsigned short f2bf(float f) {
  unsigned int u = __float_as_uint(f);
  u += 0x7FFFu + ((u >> 16) & 1u);          // RNE
  return (unsigned short)(u >> 16);
}
__device__ __forceinline__ float bf2f(unsigned short h) {
  return __uint_as_float(((unsigned int)h) << 16);
}

// ---------------------------------------------------------------------------
// Plaquette: single thread, exact fp32, matching JAX trunc-cast + python mod.
// ---------------------------------------------------------------------------
__global__ void plaq_kernel(const float* __restrict__ x,
                            const float* __restrict__ field,
                            float* __restrict__ out) {
  if (threadIdx.x != 0 || blockIdx.x != 0) return;
  int c[4];
#pragma unroll
  for (int i = 0; i < 4; ++i) {
    int v = (int)x[i];
    v %= L; if (v < 0) v += L;
    c[i] = v;
  }
  float S = 0.f;
  for (int mu = 0; mu < 4; ++mu)
    for (int nu = mu + 1; nu < 4; ++nu) {
      int p[4] = {c[0], c[1], c[2], c[3]};
      float l1 = field[((p[0]*L + p[1])*L + p[2])*4 + mu];
      p[mu] = (p[mu] + 1) % L;
      float l2 = field[((p[0]*L + p[1])*L + p[2])*4 + nu];
      p[nu] = (p[nu] + 1) % L;
      float l3 = field[((p[0]*L + p[1])*L + p[2])*4 + mu];
      float l4 = field[((c[0]*L + c[1])*L + c[2])*4 + nu];
      S += l1 + l2 - l3 - l4;
    }
  out[0] = expf(S);
}

// ---------------------------------------------------------------------------
// fc1: h = relu(x[16384,4] @ fw1[4,2048] + fb1) -> bf16.
// ---------------------------------------------------------------------------
__global__ void fc1_kernel(const float* __restrict__ x,
                           const float* __restrict__ fw1,
                           const float* __restrict__ fb1,
                           unsigned short* __restrict__ h) {
  const int N = 2048;
  int idx = blockIdx.x * blockDim.x + threadIdx.x;
  int m  = idx >> 8;
  int n0 = (idx & 255) * 8;
  float4 xv = *(const float4*)(x + (size_t)m * 4);
  unsigned short o[8];
#pragma unroll
  for (int j = 0; j < 8; ++j) {
    int n = n0 + j;
    float s = fb1[n] + xv.x * fw1[n] + xv.y * fw1[N + n]
                     + xv.z * fw1[2*N + n] + xv.w * fw1[3*N + n];
    o[j] = f2bf(fmaxf(s, 0.f));
  }
  *(u16x8*)(h + (size_t)m * N + n0) = *(const u16x8*)o;
}

// ---------------------------------------------------------------------------
// Weight transpose+convert: W[K][N] f32 -> WT[N][K] bf16.
// ---------------------------------------------------------------------------
__global__ void transpose_bf16_kernel(const float* __restrict__ W,
                                      unsigned short* __restrict__ WT,
                                      int K, int N) {
  __shared__ float tile[32][33];
  int n0 = blockIdx.x * 32, k0 = blockIdx.y * 32;
  int tx = threadIdx.x, ty = threadIdx.y;   // 32 x 8
#pragma unroll
  for (int i = 0; i < 32; i += 8)
    tile[ty + i][tx] = W[(size_t)(k0 + ty + i) * N + n0 + tx];
  __syncthreads();
#pragma unroll
  for (int i = 0; i < 32; i += 8)
    WT[(size_t)(n0 + ty + i) * K + k0 + tx] = f2bf(tile[tx][ty + i]);
}

// ---------------------------------------------------------------------------
// Elementwise f32 -> bf16 cast (natural layout), 8 elems/thread.
// ---------------------------------------------------------------------------
__global__ void cast_bf16_kernel(const float* __restrict__ in,
                                 unsigned short* __restrict__ out) {
  size_t i = ((size_t)blockIdx.x * blockDim.x + threadIdx.x) * 8;
  unsigned short o[8];
#pragma unroll
  for (int j = 0; j < 8; ++j) o[j] = f2bf(in[i + j]);
  *(u16x8*)(out + i) = *(const u16x8*)o;
}

// ---------------------------------------------------------------------------
// biascat: out[0:4096] = fb2; out[4096+m] = (m<2048?wb1[m]:tb1[m-2048])
//                                + sum_j catT[m][j]*fb2[j]    (wave per row)
// ---------------------------------------------------------------------------
__global__ void biascat_kernel(const unsigned short* __restrict__ catT,
                               const float* __restrict__ fb2,
                               const float* __restrict__ wb1,
                               const float* __restrict__ tb1,
                               float* __restrict__ out) {
  int w    = blockIdx.x * 4 + (threadIdx.x >> 6);   // 0..8191
  int lane = threadIdx.x & 63;
  if (w < 4096) { if (lane == 0) out[w] = fb2[w]; return; }
  int m = w - 4096;
  const unsigned short* row = catT + (size_t)m * 4096;
  float s = 0.f;
  for (int k = lane * 8; k < 4096; k += 512) {
    u16x8 v = *(const u16x8*)(row + k);
#pragma unroll
    for (int j = 0; j < 8; ++j) s += bf2f(v[j]) * fb2[k + j];
  }
#pragma unroll
  for (int off = 32; off; off >>= 1) s += __shfl_down(s, off);
  if (lane == 0) out[w] = s + (m < 2048 ? wb1[m] : tb1[m - 2048]);
}

// ---------------------------------------------------------------------------
// 128x128 bf16 MFMA GEMM (2 blocks/CU) for the weight product
// W2catT = (fw2 @ [ww1|tw1])^T.  C[m][n] = sum_k A[m,k]*BT[n,k], bf16 out.
// ---------------------------------------------------------------------------
__global__ __launch_bounds__(256, 2)
void gemm128_kernel(const unsigned short* __restrict__ A,
                    const unsigned short* __restrict__ BT,
                    unsigned short* __restrict__ outB,
                    int N, int K) {
  constexpr int BK = 64;
  __shared__ unsigned short As[128 * BK];
  __shared__ unsigned short Bs[128 * BK];

  const int bm = blockIdx.x, bn = blockIdx.y;
  const int tid = threadIdx.x;
  const int wid = tid >> 6, lane = tid & 63;
  const int wr = wid >> 1, wc = wid & 1;
  const int lr = lane & 15, lg = lane >> 4;

  f32x4 acc[4][4];
#pragma unroll
  for (int m = 0; m < 4; ++m)
#pragma unroll
    for (int n = 0; n < 4; ++n) acc[m][n] = (f32x4)0.f;

  const int srow = wid * 32 + (lane >> 3);
  const int scol = (lane & 7) * 8;
  const unsigned short* Ag = A  + (size_t)(bm * 128 + srow) * K + scol;
  const unsigned short* Bg = BT + (size_t)(bn * 128 + srow) * K + scol;

  for (int kt = 0; kt < K; kt += BK) {
#pragma unroll
    for (int i = 0; i < 4; ++i) {
      __builtin_amdgcn_global_load_lds(
          (const __attribute__((address_space(1))) unsigned int*)(Ag + (size_t)i * 8 * K + kt),
          (__attribute__((address_space(3))) unsigned int*)&As[wid * 2048 + i * 512],
          16, 0, 0);
      __builtin_amdgcn_global_load_lds(
          (const __attribute__((address_space(1))) unsigned int*)(Bg + (size_t)i * 8 * K + kt),
          (__attribute__((address_space(3))) unsigned int*)&Bs[wid * 2048 + i * 512],
          16, 0, 0);
    }
    __syncthreads();
#pragma unroll
    for (int kk = 0; kk < 2; ++kk) {
      u16x8 af[4], bf[4];
#pragma unroll
      for (int m = 0; m < 4; ++m)
        af[m] = *(const u16x8*)&As[(wr * 64 + m * 16 + lr) * BK + kk * 32 + lg * 8];
#pragma unroll
      for (int n = 0; n < 4; ++n)
        bf[n] = *(const u16x8*)&Bs[(wc * 64 + n * 16 + lr) * BK + kk * 32 + lg * 8];
#pragma unroll
      for (int m = 0; m < 4; ++m)
#pragma unroll
        for (int n = 0; n < 4; ++n)
          acc[m][n] = __builtin_amdgcn_mfma_f32_16x16x32_bf16(
              __builtin_bit_cast(bf16x8, af[m]),
              __builtin_bit_cast(bf16x8, bf[n]),
              acc[m][n], 0, 0, 0);
    }
    __syncthreads();
  }

  const int rowBase = bm * 128 + wr * 64 + lg * 4;
  const int colBase = bn * 128 + wc * 64 + lr;
#pragma unroll
  for (int n = 0; n < 4; ++n) {
    int col = colBase + n * 16;
#pragma unroll
    for (int m = 0; m < 4; ++m) {
      int row = rowBase + m * 16;
#pragma unroll
      for (int j = 0; j < 4; ++j)
        outB[(size_t)(row + j) * N + col] = f2bf(acc[m][n][j]);
    }
  }
}

// ---------------------------------------------------------------------------
// 256x256 bf16 MFMA GEMM, K32 slots, ring of 4 (128KB), 8 waves (2Mx4N).
// r5 schedule (counted vmcnt + counted lgkm clusters, T2/T5) with a NEW
// bn-fastest per-XCD block mapping: XCD x owns bm in [x*gmx/8, ...+gmx/8),
// sweeps bn fastest -> the XCD's resident window shares ONE A-panel (L2-hot)
// and B streams via L3 (32MB, fits). Split epilogue:
//   bn <  nFtiles : C+bias -> f32 outF (no relu), row stride NF
//   bn >= nFtiles : relu(C+bias) -> bf16 outB at col-4096, row stride NB
// ---------------------------------------------------------------------------
#define GLL(gp, lp)                                                            \
  __builtin_amdgcn_global_load_lds(                                            \
      (const __attribute__((address_space(1))) unsigned int*)(gp),             \
      (__attribute__((address_space(3))) unsigned int*)(lp), 16, 0, 0)

#define DSREAD(dst, addr)                                                      \
  asm volatile("ds_read_b128 %0, %1" : "=v"(dst) : "v"(addr))

#define LGKM(n)                                                                \
  do { asm volatile("s_waitcnt lgkmcnt(" #n ")" ::: "memory");                 \
       __builtin_amdgcn_sched_barrier(0); } while (0)

#define FENCE() asm volatile("" ::: "memory")

extern __shared__ char lds_raw[];

__global__ __launch_bounds__(512)
void gemm256_kernel(const unsigned short* __restrict__ A,
                    const unsigned short* __restrict__ BT,
                    const float* __restrict__ bias,
                    float* __restrict__ outF,
                    unsigned short* __restrict__ outB,
                    int lda, int K, int NF, int NB, int nFtiles, int gmx) {
  const int NT = K >> 5;                      // K32 tiles

  // bn-fastest per-XCD mapping (A-panel L2 reuse; B via L3)
  const int gny = gridDim.x / gmx;            // bn tile count
  const int bmPerX = gmx >> 3;                // gmx % 8 == 0
  const int xcd = blockIdx.x & 7, lid = blockIdx.x >> 3;
  const int bm = xcd * bmPerX + lid / gny;
  const int bn = lid % gny;

  const int tid  = threadIdx.x;
  const int wid  = tid >> 6, lane = tid & 63;
  const int wr   = wid >> 2, wc = wid & 3;          // 2 x 4 waves
  const int lr   = lane & 15, lg = lane >> 4;

  // ---- staging (pre-swizzled global source, linear LDS dest) ----
  const int srow = tid >> 2;
  const int scol = ((tid & 3) ^ ((tid >> 3) & 3)) * 8;   // elems
  const unsigned short* agp0 = A  + (size_t)(bm * 256 + srow) * lda + scol;
  const unsigned short* agp1 = agp0 + (size_t)128 * lda;
  const unsigned short* bgp0 = BT + (size_t)(bn * 256 + srow) * K + scol;
  const unsigned short* bgp1 = bgp0 + (size_t)128 * K;

  // ---- read-side swizzled fragment offsets (0 bank conflicts) ----
  const int chunk = lg ^ ((lr >> 1) & 3);
  const unsigned ldsbase = (unsigned)(uintptr_t)&lds_raw[0];
  const unsigned aoff = (unsigned)((wr * 128 + lr) * 64 + chunk * 16);
  const unsigned boff = (unsigned)(16384 + (wc * 64 + lr) * 64 + chunk * 16);

  f32x4 acc[8][4];
#pragma unroll
  for (int m = 0; m < 8; ++m)
#pragma unroll
    for (int n = 0; n < 4; ++n) acc[m][n] = (f32x4)0.f;

#define STAGE_A(tt) do { unsigned so = (unsigned)(((tt) & 3) << 15);           \
    GLL(agp0 + (size_t)(tt) * 32, lds_raw + so + tid * 16);                    \
    GLL(agp1 + (size_t)(tt) * 32, lds_raw + so + 8192 + tid * 16); } while (0)
#define STAGE_B(tt) do { unsigned so = (unsigned)(((tt) & 3) << 15);           \
    GLL(bgp0 + (size_t)(tt) * 32, lds_raw + so + 16384 + tid * 16);            \
    GLL(bgp1 + (size_t)(tt) * 32, lds_raw + so + 24576 + tid * 16); } while (0)

  // prologue: tiles 0,1,2 staged (12 loads in flight)
  STAGE_A(0); STAGE_B(0); STAGE_A(1); STAGE_B(1); STAGE_A(2); STAGE_B(2);

  for (int t = 0; t < NT; ++t) {
    const int rem = NT - 1 - t;
    // gate slot t (oldest 4 loads) while keeping up to 8 in flight (T4)
    if (rem >= 2)      asm volatile("s_waitcnt vmcnt(8)" ::: "memory");
    else if (rem == 1) asm volatile("s_waitcnt vmcnt(4)" ::: "memory");
    else               asm volatile("s_waitcnt vmcnt(0)" ::: "memory");
    FENCE(); __builtin_amdgcn_s_barrier(); FENCE();
    __builtin_amdgcn_sched_barrier(0);

    const unsigned sbase = ldsbase + (unsigned)((t & 3) << 15);

    // issue ALL reads in consumption order: b0-3 then a0-7
    u16x8 b[4], a[8];
    DSREAD(b[0], sbase + boff);
    DSREAD(b[1], sbase + boff + 1024);
    DSREAD(b[2], sbase + boff + 2048);
    DSREAD(b[3], sbase + boff + 3072);
    DSREAD(a[0], sbase + aoff);
    DSREAD(a[1], sbase + aoff + 1024);
    DSREAD(a[2], sbase + aoff + 2048);
    DSREAD(a[3], sbase + aoff + 3072);
    DSREAD(a[4], sbase + aoff + 4096);
    DSREAD(a[5], sbase + aoff + 5120);
    DSREAD(a[6], sbase + aoff + 6144);
    DSREAD(a[7], sbase + aoff + 7168);
    // stage tile t+3 into slot (t-1)&3 — safe after this tile's barrier
    if (t + 3 < NT) { STAGE_A(t + 3); STAGE_B(t + 3); }

    // 8 clusters: counted lgkm gate -> 4 MFMA; LDS serves ahead under MFMA
    __builtin_amdgcn_s_setprio(1);
#define CLUSTER(m, g)                                                          \
    LGKM(g);                                                                   \
    acc[m][0] = __builtin_amdgcn_mfma_f32_16x16x32_bf16(                       \
        __builtin_bit_cast(bf16x8, a[m]), __builtin_bit_cast(bf16x8, b[0]),    \
        acc[m][0], 0, 0, 0);                                                   \
    acc[m][1] = __builtin_amdgcn_mfma_f32_16x16x32_bf16(                       \
        __builtin_bit_cast(bf16x8, a[m]), __builtin_bit_cast(bf16x8, b[1]),    \
        acc[m][1], 0, 0, 0);                                                   \
    acc[m][2] = __builtin_amdgcn_mfma_f32_16x16x32_bf16(                       \
        __builtin_bit_cast(bf16x8, a[m]), __builtin_bit_cast(bf16x8, b[2]),    \
        acc[m][2], 0, 0, 0);                                                   \
    acc[m][3] = __builtin_amdgcn_mfma_f32_16x16x32_bf16(                       \
        __builtin_bit_cast(bf16x8, a[m]), __builtin_bit_cast(bf16x8, b[3]),    \
        acc[m][3], 0, 0, 0)

    CLUSTER(0, 7);
    CLUSTER(1, 6);
    CLUSTER(2, 5);
    CLUSTER(3, 4);
    CLUSTER(4, 3);
    CLUSTER(5, 2);
    CLUSTER(6, 1);
    CLUSTER(7, 0);
#undef CLUSTER
    __builtin_amdgcn_s_setprio(0);
    __builtin_amdgcn_sched_barrier(0);
  }
#undef STAGE_A
#undef STAGE_B

  const int rowBase = bm * 256 + wr * 128 + lg * 4;
  const int colBase = bn * 256 + wc * 64 + lr;
  if (bn < nFtiles) {
#pragma unroll
    for (int n = 0; n < 4; ++n) {
      int col = colBase + n * 16;
      float bv = bias[col];
#pragma unroll
      for (int m = 0; m < 8; ++m) {
        int row = rowBase + m * 16;
#pragma unroll
        for (int j = 0; j < 4; ++j)
          outF[(size_t)(row + j) * NF + col] = acc[m][n][j] + bv;
      }
    }
  } else {
    const int colB = colBase - nFtiles * 256;
#pragma unroll
    for (int n = 0; n < 4; ++n) {
      int col = colB + n * 16;
      float bv = bias[colBase + n * 16];
#pragma unroll
      for (int m = 0; m < 8; ++m) {
        int row = rowBase + m * 16;
#pragma unroll
        for (int j = 0; j < 4; ++j)
          outB[(size_t)(row + j) * NB + col] = f2bf(fmaxf(acc[m][n][j] + bv, 0.f));
      }
    }
  }
}

// ---------------------------------------------------------------------------
// GEMV head: out[m] = sum_k A[m*lda+k]*w[k] + b.  One wave per row.
// ---------------------------------------------------------------------------
__global__ void gemv_kernel(const unsigned short* __restrict__ Abf,
                            const float* __restrict__ wvec,
                            const float* __restrict__ bias,
                            float* __restrict__ out, int K, int lda) {
  int row  = blockIdx.x * 4 + (threadIdx.x >> 6);
  int lane = threadIdx.x & 63;
  const unsigned short* ap = Abf + (size_t)row * lda;
  float s = 0.f;
  for (int k = lane * 8; k < K; k += 512) {
    u16x8 v = *(const u16x8*)(ap + k);
#pragma unroll
    for (int j = 0; j < 8; ++j) s += bf2f(v[j]) * wvec[k + j];
  }
#pragma unroll
  for (int off = 32; off; off >>= 1) s += __shfl_down(s, off);
  if (lane == 0) out[row] = s + bias[0];
}

// ---------------------------------------------------------------------------
extern "C" void kernel_launch(void* const* d_in, const int* in_sizes, int n_in,
                              void* d_out, int out_size, void* d_ws, size_t ws_size,
                              hipStream_t stream) {
  const float* x     = (const float*)d_in[0];
  const float* field = (const float*)d_in[1];
  const float* fw1   = (const float*)d_in[2];
  const float* fb1   = (const float*)d_in[3];
  const float* fw2   = (const float*)d_in[4];
  const float* fb2   = (const float*)d_in[5];
  const float* ww1   = (const float*)d_in[6];
  const float* wb1   = (const float*)d_in[7];
  const float* ww2   = (const float*)d_in[8];
  const float* wb2   = (const float*)d_in[9];
  const float* ww3   = (const float*)d_in[10];
  const float* wb3   = (const float*)d_in[11];
  const float* tw1   = (const float*)d_in[12];
  const float* tb1   = (const float*)d_in[13];
  const float* tw2   = (const float*)d_in[14];
  const float* tb2   = (const float*)d_in[15];

  const int M = 16384;
  float* outF    = (float*)d_out;                  // field_output [16384,4096]
  float* outWil  = outF + (size_t)M * 4096;
  float* outTop  = outWil + M;
  float* outPlaq = outTop + M;

  char* ws = (char*)d_ws;
  const size_t MB = 1048576;
  unsigned short* hbuf    = (unsigned short*)(ws);              // [16384,2048] 64MB
  unsigned short* catbuf  = (unsigned short*)(ws + 64  * MB);   // [16384,4096] 128MB (w1|t)
  unsigned short* catT    = (unsigned short*)(ws + 192 * MB);   // [4096,4096]  32MB (dead after GEMM_W)
  unsigned short* w2buf   = (unsigned short*)(ws + 192 * MB);   // [16384,1024] 32MB (reuses catT)
  unsigned short* fw2T    = (unsigned short*)(ws + 224 * MB);   // [4096,2048]  16MB  \ contiguous =
  unsigned short* W2catT  = (unsigned short*)(ws + 240 * MB);   // [4096,2048]  16MB  / BTcat [8192,2048]
  unsigned short* BTcat   = fw2T;
  unsigned short* fw2bf   = (unsigned short*)(ws + 256 * MB);   // [2048,4096]  16MB
  unsigned short* ww2T    = (unsigned short*)(ws + 272 * MB);   // [1024,2048]  4MB
  float*          biascat = (float*)(ws + 276 * MB);            // [8192] 32KB

  const int SMEM = 131072;   // 4-slot ring
  (void)hipFuncSetAttribute((const void*)gemm256_kernel,
                            hipFuncAttributeMaxDynamicSharedMemorySize, SMEM);

  // independent prep
  hipLaunchKernelGGL(plaq_kernel, dim3(1), dim3(64), 0, stream, x, field, outPlaq);
  hipLaunchKernelGGL(fc1_kernel, dim3(16384), dim3(256), 0, stream, x, fw1, fb1, hbuf);
  hipLaunchKernelGGL(transpose_bf16_kernel, dim3(128, 64), dim3(32, 8), 0, stream,
                     fw2, fw2T, 2048, 4096);
  hipLaunchKernelGGL(cast_bf16_kernel, dim3(4096), dim3(256), 0, stream, fw2, fw2bf);
  hipLaunchKernelGGL(transpose_bf16_kernel, dim3(64, 128), dim3(32, 8), 0, stream,
                     ww1, catT, 4096, 2048);
  hipLaunchKernelGGL(transpose_bf16_kernel, dim3(64, 128), dim3(32, 8), 0, stream,
                     tw1, catT + (size_t)2048 * 4096, 4096, 2048);
  hipLaunchKernelGGL(transpose_bf16_kernel, dim3(32, 64), dim3(32, 8), 0, stream,
                     ww2, ww2T, 2048, 1024);
  hipLaunchKernelGGL(biascat_kernel, dim3(2048), dim3(256), 0, stream,
                     catT, fb2, wb1, tb1, biascat);

  // W2catT[n][k] = sum_j catT[n][j] * fw2bf[k][j]   (M=4096, N=2048, K=4096)
  hipLaunchKernelGGL(gemm128_kernel, dim3(32, 16), dim3(256), 0, stream,
                     catT, fw2bf, W2catT, 2048, 4096);

  // fused: C = h @ [fw2 | W2cat] + biascat   (M=16384, N=8192, K=2048)
  //   bn<16: field_output f32 -> outF;  bn>=16: relu bf16 -> catbuf
  hipLaunchKernelGGL(gemm256_kernel, dim3(64 * 32), dim3(512), SMEM, stream,
                     hbuf, BTcat, biascat, outF, catbuf,
                     2048, 2048, 4096, 4096, 16, 64);

  // w2 = relu(w1 @ ww2 + wb2)   (A = catbuf cols 0..2047, lda 4096)
  hipLaunchKernelGGL(gemm256_kernel, dim3(64 * 4), dim3(512), SMEM, stream,
                     catbuf, ww2T, wb2, (float*)nullptr, w2buf,
                     4096, 2048, 0, 1024, 0, 64);

  // heads
  hipLaunchKernelGGL(gemv_kernel, dim3(4096), dim3(256), 0, stream,
                     w2buf, ww3, wb3, outWil, 1024, 1024);
  hipLaunchKernelGGL(gemv_kernel, dim3(4096), dim3(256), 0, stream,
                     catbuf + 2048, tw2, tb2, outTop, 2048, 4096);

  (void)in_sizes; (void)n_in; (void)out_size; (void)ws_size;
}

// Round 10
// 918.070 us; speedup vs baseline: 7.6549x; 1.0287x over previous
//
#include <hip/hip_runtime.h>

#define L 10

using bf16x8 = __attribute__((ext_vector_type(8))) __bf16;
using u16x8  = __attribute__((ext_vector_type(8))) unsigned short;
using f32x4  = __attribute__((ext_vector_type(4))) float;

__device__ __forceinline__ unsigned short f2bf(float f) {
  unsigned int u = __float_as_uint(f);
  u += 0x7FFFu + ((u >> 16) & 1u);          // RNE
  return (unsigned short)(u >> 16);
}
__device__ __forceinline__ float bf2f(unsigned short h) {
  return __uint_as_float(((unsigned int)h) << 16);
}

// ---------------------------------------------------------------------------
// Plaquette: single thread, exact fp32, matching JAX trunc-cast + python mod.
// ---------------------------------------------------------------------------
__global__ void plaq_kernel(const float* __restrict__ x,
                            const float* __restrict__ field,
                            float* __restrict__ out) {
  if (threadIdx.x != 0 || blockIdx.x != 0) return;
  int c[4];
#pragma unroll
  for (int i = 0; i < 4; ++i) {
    int v = (int)x[i];
    v %= L; if (v < 0) v += L;
    c[i] = v;
  }
  float S = 0.f;
  for (int mu = 0; mu < 4; ++mu)
    for (int nu = mu + 1; nu < 4; ++nu) {
      int p[4] = {c[0], c[1], c[2], c[3]};
      float l1 = field[((p[0]*L + p[1])*L + p[2])*4 + mu];
      p[mu] = (p[mu] + 1) % L;
      float l2 = field[((p[0]*L + p[1])*L + p[2])*4 + nu];
      p[nu] = (p[nu] + 1) % L;
      float l3 = field[((p[0]*L + p[1])*L + p[2])*4 + mu];
      float l4 = field[((c[0]*L + c[1])*L + c[2])*4 + nu];
      S += l1 + l2 - l3 - l4;
    }
  out[0] = expf(S);
}

// ---------------------------------------------------------------------------
// fc1: h = relu(x[16384,4] @ fw1[4,2048] + fb1) -> bf16.
// ---------------------------------------------------------------------------
__global__ void fc1_kernel(const float* __restrict__ x,
                           const float* __restrict__ fw1,
                           const float* __restrict__ fb1,
                           unsigned short* __restrict__ h) {
  const int N = 2048;
  int idx = blockIdx.x * blockDim.x + threadIdx.x;
  int m  = idx >> 8;
  int n0 = (idx & 255) * 8;
  float4 xv = *(const float4*)(x + (size_t)m * 4);
  unsigned short o[8];
#pragma unroll
  for (int j = 0; j < 8; ++j) {
    int n = n0 + j;
    float s = fb1[n] + xv.x * fw1[n] + xv.y * fw1[N + n]
                     + xv.z * fw1[2*N + n] + xv.w * fw1[3*N + n];
    o[j] = f2bf(fmaxf(s, 0.f));
  }
  *(u16x8*)(h + (size_t)m * N + n0) = *(const u16x8*)o;
}

// ---------------------------------------------------------------------------
// Weight transpose+convert: W[K][N] f32 -> WT[N][K] bf16.
// ---------------------------------------------------------------------------
__global__ void transpose_bf16_kernel(const float* __restrict__ W,
                                      unsigned short* __restrict__ WT,
                                      int K, int N) {
  __shared__ float tile[32][33];
  int n0 = blockIdx.x * 32, k0 = blockIdx.y * 32;
  int tx = threadIdx.x, ty = threadIdx.y;   // 32 x 8
#pragma unroll
  for (int i = 0; i < 32; i += 8)
    tile[ty + i][tx] = W[(size_t)(k0 + ty + i) * N + n0 + tx];
  __syncthreads();
#pragma unroll
  for (int i = 0; i < 32; i += 8)
    WT[(size_t)(n0 + ty + i) * K + k0 + tx] = f2bf(tile[tx][ty + i]);
}

// ---------------------------------------------------------------------------
// Elementwise f32 -> bf16 cast (natural layout), 8 elems/thread.
// ---------------------------------------------------------------------------
__global__ void cast_bf16_kernel(const float* __restrict__ in,
                                 unsigned short* __restrict__ out) {
  size_t i = ((size_t)blockIdx.x * blockDim.x + threadIdx.x) * 8;
  unsigned short o[8];
#pragma unroll
  for (int j = 0; j < 8; ++j) o[j] = f2bf(in[i + j]);
  *(u16x8*)(out + i) = *(const u16x8*)o;
}

// ---------------------------------------------------------------------------
// biascat: out[0:4096] = fb2; out[4096+m] = (m<2048?wb1[m]:tb1[m-2048])
//                                + sum_j catT[m][j]*fb2[j]    (wave per row)
// ---------------------------------------------------------------------------
__global__ void biascat_kernel(const unsigned short* __restrict__ catT,
                               const float* __restrict__ fb2,
                               const float* __restrict__ wb1,
                               const float* __restrict__ tb1,
                               float* __restrict__ out) {
  int w    = blockIdx.x * 4 + (threadIdx.x >> 6);   // 0..8191
  int lane = threadIdx.x & 63;
  if (w < 4096) { if (lane == 0) out[w] = fb2[w]; return; }
  int m = w - 4096;
  const unsigned short* row = catT + (size_t)m * 4096;
  float s = 0.f;
  for (int k = lane * 8; k < 4096; k += 512) {
    u16x8 v = *(const u16x8*)(row + k);
#pragma unroll
    for (int j = 0; j < 8; ++j) s += bf2f(v[j]) * fb2[k + j];
  }
#pragma unroll
  for (int off = 32; off; off >>= 1) s += __shfl_down(s, off);
  if (lane == 0) out[w] = s + (m < 2048 ? wb1[m] : tb1[m - 2048]);
}

// ---------------------------------------------------------------------------
// 128x128 bf16 MFMA GEMM (2 blocks/CU) for the weight product
// W2catT = (fw2 @ [ww1|tw1])^T.  C[m][n] = sum_k A[m,k]*BT[n,k], bf16 out.
// (cached stores: W2catT is read immediately by the big GEMM)
// ---------------------------------------------------------------------------
__global__ __launch_bounds__(256, 2)
void gemm128_kernel(const unsigned short* __restrict__ A,
                    const unsigned short* __restrict__ BT,
                    unsigned short* __restrict__ outB,
                    int N, int K) {
  constexpr int BK = 64;
  __shared__ unsigned short As[128 * BK];
  __shared__ unsigned short Bs[128 * BK];

  const int bm = blockIdx.x, bn = blockIdx.y;
  const int tid = threadIdx.x;
  const int wid = tid >> 6, lane = tid & 63;
  const int wr = wid >> 1, wc = wid & 1;
  const int lr = lane & 15, lg = lane >> 4;

  f32x4 acc[4][4];
#pragma unroll
  for (int m = 0; m < 4; ++m)
#pragma unroll
    for (int n = 0; n < 4; ++n) acc[m][n] = (f32x4)0.f;

  const int srow = wid * 32 + (lane >> 3);
  const int scol = (lane & 7) * 8;
  const unsigned short* Ag = A  + (size_t)(bm * 128 + srow) * K + scol;
  const unsigned short* Bg = BT + (size_t)(bn * 128 + srow) * K + scol;

  for (int kt = 0; kt < K; kt += BK) {
#pragma unroll
    for (int i = 0; i < 4; ++i) {
      __builtin_amdgcn_global_load_lds(
          (const __attribute__((address_space(1))) unsigned int*)(Ag + (size_t)i * 8 * K + kt),
          (__attribute__((address_space(3))) unsigned int*)&As[wid * 2048 + i * 512],
          16, 0, 0);
      __builtin_amdgcn_global_load_lds(
          (const __attribute__((address_space(1))) unsigned int*)(Bg + (size_t)i * 8 * K + kt),
          (__attribute__((address_space(3))) unsigned int*)&Bs[wid * 2048 + i * 512],
          16, 0, 0);
    }
    __syncthreads();
#pragma unroll
    for (int kk = 0; kk < 2; ++kk) {
      u16x8 af[4], bf[4];
#pragma unroll
      for (int m = 0; m < 4; ++m)
        af[m] = *(const u16x8*)&As[(wr * 64 + m * 16 + lr) * BK + kk * 32 + lg * 8];
#pragma unroll
      for (int n = 0; n < 4; ++n)
        bf[n] = *(const u16x8*)&Bs[(wc * 64 + n * 16 + lr) * BK + kk * 32 + lg * 8];
#pragma unroll
      for (int m = 0; m < 4; ++m)
#pragma unroll
        for (int n = 0; n < 4; ++n)
          acc[m][n] = __builtin_amdgcn_mfma_f32_16x16x32_bf16(
              __builtin_bit_cast(bf16x8, af[m]),
              __builtin_bit_cast(bf16x8, bf[n]),
              acc[m][n], 0, 0, 0);
    }
    __syncthreads();
  }

  const int rowBase = bm * 128 + wr * 64 + lg * 4;
  const int colBase = bn * 128 + wc * 64 + lr;
#pragma unroll
  for (int n = 0; n < 4; ++n) {
    int col = colBase + n * 16;
#pragma unroll
    for (int m = 0; m < 4; ++m) {
      int row = rowBase + m * 16;
#pragma unroll
      for (int j = 0; j < 4; ++j)
        outB[(size_t)(row + j) * N + col] = f2bf(acc[m][n][j]);
    }
  }
}

// ---------------------------------------------------------------------------
// 256x256 bf16 MFMA GEMM, K32 slots, ring of 4 (128KB), 8 waves (2Mx4N).
// r5 schedule (counted vmcnt + counted lgkm clusters, T2/T5) and r5's T1
// bm-fastest XCD swizzle (r9's bn-fastest regressed — reverted). NEW:
// NON-TEMPORAL epilogue stores — the 560MB/dispatch write stream bypasses
// L2/L3 allocation so the L3-resident A/B panels stop being evicted
// (FETCH was 11x compulsory; write-eviction is the suspected mechanism).
// Split epilogue:
//   bn <  nFtiles : C+bias -> f32 outF (no relu), row stride NF
//   bn >= nFtiles : relu(C+bias) -> bf16 outB at col-4096, row stride NB
// ---------------------------------------------------------------------------
#define GLL(gp, lp)                                                            \
  __builtin_amdgcn_global_load_lds(                                            \
      (const __attribute__((address_space(1))) unsigned int*)(gp),             \
      (__attribute__((address_space(3))) unsigned int*)(lp), 16, 0, 0)

#define DSREAD(dst, addr)                                                      \
  asm volatile("ds_read_b128 %0, %1" : "=v"(dst) : "v"(addr))

#define LGKM(n)                                                                \
  do { asm volatile("s_waitcnt lgkmcnt(" #n ")" ::: "memory");                 \
       __builtin_amdgcn_sched_barrier(0); } while (0)

#define FENCE() asm volatile("" ::: "memory")

extern __shared__ char lds_raw[];

__global__ __launch_bounds__(512)
void gemm256_kernel(const unsigned short* __restrict__ A,
                    const unsigned short* __restrict__ BT,
                    const float* __restrict__ bias,
                    float* __restrict__ outF,
                    unsigned short* __restrict__ outB,
                    int lda, int K, int NF, int NB, int nFtiles, int gmx) {
  const int NT = K >> 5;                      // K32 tiles

  // T1: bijective XCD swizzle, bm fastest (r5-proven)
  const int nwg = gridDim.x;
  const int q = nwg >> 3, r = nwg & 7;
  const int xcd = blockIdx.x & 7, lid = blockIdx.x >> 3;
  const int wg2 = (xcd < r ? xcd * (q + 1) : r * (q + 1) + (xcd - r) * q) + lid;
  const int bm = wg2 % gmx, bn = wg2 / gmx;

  const int tid  = threadIdx.x;
  const int wid  = tid >> 6, lane = tid & 63;
  const int wr   = wid >> 2, wc = wid & 3;          // 2 x 4 waves
  const int lr   = lane & 15, lg = lane >> 4;

  // ---- staging (pre-swizzled global source, linear LDS dest) ----
  const int srow = tid >> 2;
  const int scol = ((tid & 3) ^ ((tid >> 3) & 3)) * 8;   // elems
  const unsigned short* agp0 = A  + (size_t)(bm * 256 + srow) * lda + scol;
  const unsigned short* agp1 = agp0 + (size_t)128 * lda;
  const unsigned short* bgp0 = BT + (size_t)(bn * 256 + srow) * K + scol;
  const unsigned short* bgp1 = bgp0 + (size_t)128 * K;

  // ---- read-side swizzled fragment offsets (0 bank conflicts) ----
  const int chunk = lg ^ ((lr >> 1) & 3);
  const unsigned ldsbase = (unsigned)(uintptr_t)&lds_raw[0];
  const unsigned aoff = (unsigned)((wr * 128 + lr) * 64 + chunk * 16);
  const unsigned boff = (unsigned)(16384 + (wc * 64 + lr) * 64 + chunk * 16);

  f32x4 acc[8][4];
#pragma unroll
  for (int m = 0; m < 8; ++m)
#pragma unroll
    for (int n = 0; n < 4; ++n) acc[m][n] = (f32x4)0.f;

#define STAGE_A(tt) do { unsigned so = (unsigned)(((tt) & 3) << 15);           \
    GLL(agp0 + (size_t)(tt) * 32, lds_raw + so + tid * 16);                    \
    GLL(agp1 + (size_t)(tt) * 32, lds_raw + so + 8192 + tid * 16); } while (0)
#define STAGE_B(tt) do { unsigned so = (unsigned)(((tt) & 3) << 15);           \
    GLL(bgp0 + (size_t)(tt) * 32, lds_raw + so + 16384 + tid * 16);            \
    GLL(bgp1 + (size_t)(tt) * 32, lds_raw + so + 24576 + tid * 16); } while (0)

  // prologue: tiles 0,1,2 staged (12 loads in flight)
  STAGE_A(0); STAGE_B(0); STAGE_A(1); STAGE_B(1); STAGE_A(2); STAGE_B(2);

  for (int t = 0; t < NT; ++t) {
    const int rem = NT - 1 - t;
    // gate slot t (oldest 4 loads) while keeping up to 8 in flight (T4)
    if (rem >= 2)      asm volatile("s_waitcnt vmcnt(8)" ::: "memory");
    else if (rem == 1) asm volatile("s_waitcnt vmcnt(4)" ::: "memory");
    else               asm volatile("s_waitcnt vmcnt(0)" ::: "memory");
    FENCE(); __builtin_amdgcn_s_barrier(); FENCE();
    __builtin_amdgcn_sched_barrier(0);

    const unsigned sbase = ldsbase + (unsigned)((t & 3) << 15);

    // issue ALL reads in consumption order: b0-3 then a0-7
    u16x8 b[4], a[8];
    DSREAD(b[0], sbase + boff);
    DSREAD(b[1], sbase + boff + 1024);
    DSREAD(b[2], sbase + boff + 2048);
    DSREAD(b[3], sbase + boff + 3072);
    DSREAD(a[0], sbase + aoff);
    DSREAD(a[1], sbase + aoff + 1024);
    DSREAD(a[2], sbase + aoff + 2048);
    DSREAD(a[3], sbase + aoff + 3072);
    DSREAD(a[4], sbase + aoff + 4096);
    DSREAD(a[5], sbase + aoff + 5120);
    DSREAD(a[6], sbase + aoff + 6144);
    DSREAD(a[7], sbase + aoff + 7168);
    // stage tile t+3 into slot (t-1)&3 — safe after this tile's barrier
    if (t + 3 < NT) { STAGE_A(t + 3); STAGE_B(t + 3); }

    // 8 clusters: counted lgkm gate -> 4 MFMA; LDS serves ahead under MFMA
    __builtin_amdgcn_s_setprio(1);
#define CLUSTER(m, g)                                                          \
    LGKM(g);                                                                   \
    acc[m][0] = __builtin_amdgcn_mfma_f32_16x16x32_bf16(                       \
        __builtin_bit_cast(bf16x8, a[m]), __builtin_bit_cast(bf16x8, b[0]),    \
        acc[m][0], 0, 0, 0);                                                   \
    acc[m][1] = __builtin_amdgcn_mfma_f32_16x16x32_bf16(                       \
        __builtin_bit_cast(bf16x8, a[m]), __builtin_bit_cast(bf16x8, b[1]),    \
        acc[m][1], 0, 0, 0);                                                   \
    acc[m][2] = __builtin_amdgcn_mfma_f32_16x16x32_bf16(                       \
        __builtin_bit_cast(bf16x8, a[m]), __builtin_bit_cast(bf16x8, b[2]),    \
        acc[m][2], 0, 0, 0);                                                   \
    acc[m][3] = __builtin_amdgcn_mfma_f32_16x16x32_bf16(                       \
        __builtin_bit_cast(bf16x8, a[m]), __builtin_bit_cast(bf16x8, b[3]),    \
        acc[m][3], 0, 0, 0)

    CLUSTER(0, 7);
    CLUSTER(1, 6);
    CLUSTER(2, 5);
    CLUSTER(3, 4);
    CLUSTER(4, 3);
    CLUSTER(5, 2);
    CLUSTER(6, 1);
    CLUSTER(7, 0);
#undef CLUSTER
    __builtin_amdgcn_s_setprio(0);
    __builtin_amdgcn_sched_barrier(0);
  }
#undef STAGE_A
#undef STAGE_B

  // epilogue: non-temporal stores — do not pollute L2/L3 (keep A/B resident)
  const int rowBase = bm * 256 + wr * 128 + lg * 4;
  const int colBase = bn * 256 + wc * 64 + lr;
  if (bn < nFtiles) {
#pragma unroll
    for (int n = 0; n < 4; ++n) {
      int col = colBase + n * 16;
      float bv = bias[col];
#pragma unroll
      for (int m = 0; m < 8; ++m) {
        int row = rowBase + m * 16;
#pragma unroll
        for (int j = 0; j < 4; ++j)
          __builtin_nontemporal_store(acc[m][n][j] + bv,
                                      &outF[(size_t)(row + j) * NF + col]);
      }
    }
  } else {
    const int colB = colBase - nFtiles * 256;
#pragma unroll
    for (int n = 0; n < 4; ++n) {
      int col = colB + n * 16;
      float bv = bias[colBase + n * 16];
#pragma unroll
      for (int m = 0; m < 8; ++m) {
        int row = rowBase + m * 16;
#pragma unroll
        for (int j = 0; j < 4; ++j)
          __builtin_nontemporal_store(f2bf(fmaxf(acc[m][n][j] + bv, 0.f)),
                                      &outB[(size_t)(row + j) * NB + colB + n * 16]);
      }
    }
  }
}

// ---------------------------------------------------------------------------
// GEMV head: out[m] = sum_k A[m*lda+k]*w[k] + b.  One wave per row.
// ---------------------------------------------------------------------------
__global__ void gemv_kernel(const unsigned short* __restrict__ Abf,
                            const float* __restrict__ wvec,
                            const float* __restrict__ bias,
                            float* __restrict__ out, int K, int lda) {
  int row  = blockIdx.x * 4 + (threadIdx.x >> 6);
  int lane = threadIdx.x & 63;
  const unsigned short* ap = Abf + (size_t)row * lda;
  float s = 0.f;
  for (int k = lane * 8; k < K; k += 512) {
    u16x8 v = *(const u16x8*)(ap + k);
#pragma unroll
    for (int j = 0; j < 8; ++j) s += bf2f(v[j]) * wvec[k + j];
  }
#pragma unroll
  for (int off = 32; off; off >>= 1) s += __shfl_down(s, off);
  if (lane == 0) out[row] = s + bias[0];
}

// ---------------------------------------------------------------------------
extern "C" void kernel_launch(void* const* d_in, const int* in_sizes, int n_in,
                              void* d_out, int out_size, void* d_ws, size_t ws_size,
                              hipStream_t stream) {
  const float* x     = (const float*)d_in[0];
  const float* field = (const float*)d_in[1];
  const float* fw1   = (const float*)d_in[2];
  const float* fb1   = (const float*)d_in[3];
  const float* fw2   = (const float*)d_in[4];
  const float* fb2   = (const float*)d_in[5];
  const float* ww1   = (const float*)d_in[6];
  const float* wb1   = (const float*)d_in[7];
  const float* ww2   = (const float*)d_in[8];
  const float* wb2   = (const float*)d_in[9];
  const float* ww3   = (const float*)d_in[10];
  const float* wb3   = (const float*)d_in[11];
  const float* tw1   = (const float*)d_in[12];
  const float* tb1   = (const float*)d_in[13];
  const float* tw2   = (const float*)d_in[14];
  const float* tb2   = (const float*)d_in[15];

  const int M = 16384;
  float* outF    = (float*)d_out;                  // field_output [16384,4096]
  float* outWil  = outF + (size_t)M * 4096;
  float* outTop  = outWil + M;
  float* outPlaq = outTop + M;

  char* ws = (char*)d_ws;
  const size_t MB = 1048576;
  unsigned short* hbuf    = (unsigned short*)(ws);              // [16384,2048] 64MB
  unsigned short* catbuf  = (unsigned short*)(ws + 64  * MB);   // [16384,4096] 128MB (w1|t)
  unsigned short* catT    = (unsigned short*)(ws + 192 * MB);   // [4096,4096]  32MB (dead after GEMM_W)
  unsigned short* w2buf   = (unsigned short*)(ws + 192 * MB);   // [16384,1024] 32MB (reuses catT)
  unsigned short* fw2T    = (unsigned short*)(ws + 224 * MB);   // [4096,2048]  16MB  \ contiguous =
  unsigned short* W2catT  = (unsigned short*)(ws + 240 * MB);   // [4096,2048]  16MB  / BTcat [8192,2048]
  unsigned short* BTcat   = fw2T;
  unsigned short* fw2bf   = (unsigned short*)(ws + 256 * MB);   // [2048,4096]  16MB
  unsigned short* ww2T    = (unsigned short*)(ws + 272 * MB);   // [1024,2048]  4MB
  float*          biascat = (float*)(ws + 276 * MB);            // [8192] 32KB

  const int SMEM = 131072;   // 4-slot ring
  (void)hipFuncSetAttribute((const void*)gemm256_kernel,
                            hipFuncAttributeMaxDynamicSharedMemorySize, SMEM);

  // independent prep
  hipLaunchKernelGGL(plaq_kernel, dim3(1), dim3(64), 0, stream, x, field, outPlaq);
  hipLaunchKernelGGL(fc1_kernel, dim3(16384), dim3(256), 0, stream, x, fw1, fb1, hbuf);
  hipLaunchKernelGGL(transpose_bf16_kernel, dim3(128, 64), dim3(32, 8), 0, stream,
                     fw2, fw2T, 2048, 4096);
  hipLaunchKernelGGL(cast_bf16_kernel, dim3(4096), dim3(256), 0, stream, fw2, fw2bf);
  hipLaunchKernelGGL(transpose_bf16_kernel, dim3(64, 128), dim3(32, 8), 0, stream,
                     ww1, catT, 4096, 2048);
  hipLaunchKernelGGL(transpose_bf16_kernel, dim3(64, 128), dim3(32, 8), 0, stream,
                     tw1, catT + (size_t)2048 * 4096, 4096, 2048);
  hipLaunchKernelGGL(transpose_bf16_kernel, dim3(32, 64), dim3(32, 8), 0, stream,
                     ww2, ww2T, 2048, 1024);
  hipLaunchKernelGGL(biascat_kernel, dim3(2048), dim3(256), 0, stream,
                     catT, fb2, wb1, tb1, biascat);

  // W2catT[n][k] = sum_j catT[n][j] * fw2bf[k][j]   (M=4096, N=2048, K=4096)
  hipLaunchKernelGGL(gemm128_kernel, dim3(32, 16), dim3(256), 0, stream,
                     catT, fw2bf, W2catT, 2048, 4096);

  // fused: C = h @ [fw2 | W2cat] + biascat   (M=16384, N=8192, K=2048)
  //   bn<16: field_output f32 -> outF;  bn>=16: relu bf16 -> catbuf
  hipLaunchKernelGGL(gemm256_kernel, dim3(64 * 32), dim3(512), SMEM, stream,
                     hbuf, BTcat, biascat, outF, catbuf,
                     2048, 2048, 4096, 4096, 16, 64);

  // w2 = relu(w1 @ ww2 + wb2)   (A = catbuf cols 0..2047, lda 4096)
  hipLaunchKernelGGL(gemm256_kernel, dim3(64 * 4), dim3(512), SMEM, stream,
                     catbuf, ww2T, wb2, (float*)nullptr, w2buf,
                     4096, 2048, 0, 1024, 0, 64);

  // heads
  hipLaunchKernelGGL(gemv_kernel, dim3(4096), dim3(256), 0, stream,
                     w2buf, ww3, wb3, outWil, 1024, 1024);
  hipLaunchKernelGGL(gemv_kernel, dim3(4096), dim3(256), 0, stream,
                     catbuf + 2048, tw2, tb2, outTop, 2048, 4096);

  (void)in_sizes; (void)n_in; (void)out_size; (void)ws_size;
}